// Round 1
// baseline (215.982 us; speedup 1.0000x reference)
//
#include <hip/hip_runtime.h>
#include <hip/hip_bf16.h>

#define N_ 32
#define C_ 128
#define H_ 48
#define W_ 48
#define P_ (H_*W_)   // 2304
#define K_ 64
#define S_ 4
#define L_ 3
#define R_ 21
#define NB_ 72       // P_/32 pixel tiles per image
#define M_ 512       // total logit rows
#define CH_ 9        // vlad chunks (256 px each)

typedef __hip_bfloat16 bf16;
typedef __attribute__((ext_vector_type(8))) short   bf16x8;
typedef __attribute__((ext_vector_type(8))) unsigned short u16x8;
typedef __attribute__((ext_vector_type(4))) float   f32x4;

__device__ __forceinline__ float b2f(bf16 v){ return __bfloat162float(v); }
__device__ __forceinline__ float u2f(unsigned short u){
  union { unsigned i; float f; } v; v.i = ((unsigned)u) << 16; return v.f;
}
__device__ __forceinline__ unsigned short f2u(float f){
  bf16 h = __float2bfloat16(f);
  return *(unsigned short*)&h;
}

// wave-uniform dtype probe: 1 if x is fp32, 0 if bf16 (reads fixed 1024-elem window).
__device__ __forceinline__ int is_f32(const unsigned short* __restrict__ xb){
  int lane = threadIdx.x & 63;
  int w = 0;
  #pragma unroll
  for (int i=0;i<16;++i){
    int e = (xb[lane*16 + i] >> 7) & 0xFF;
    w += (e >= 0x8E) ? 1 : 0;
  }
  unsigned long long b = __ballot(w > 0);
  return __popcll(b) > 32;
}

// region membership for global region index r (0..20) at pixel (h,w); bf16 1.0/0.0 bits
__device__ __forceinline__ unsigned short region_bit(int r, int h, int w){
  bool m;
  if (r == 0){
    m = true;
  } else if (r < 5){
    int q = r-1, i = q>>1, j = q&1;
    m = (h>=16*i)&&(h<16*i+32)&&(w>=16*j)&&(w<16*j+32);
  } else if (r < 21){
    int q = r-5, i = q>>2, j = q&3;
    m = (h>=10*i-1)&&(h<10*i+19)&&(w>=10*j-1)&&(w<10*j+19);
  } else {
    m = false;
  }
  return m ? (unsigned short)0x3F80 : (unsigned short)0;
}

// ---------- K0: build WallF in MFMA-fragment order ----------
// frag f = (((wv*8+rt)*4+ks)*64 + lane)*8 + j  <-  row = wv*128+rt*16+(lane&15),
// c = ks*32 + ((lane>>4)&3)*8 + j. Rows: 0-63 score, 64-319 shadow, 320-511 app.
__global__ __launch_bounds__(256) void k_wall(const void* __restrict__ cvw, const void* __restrict__ csw,
                                              const void* __restrict__ caw, const void* __restrict__ x,
                                              bf16* __restrict__ WallF){
  int f32 = is_f32((const unsigned short*)x);
  int i = blockIdx.x*256 + threadIdx.x;          // 0..65535
  int j = i&7, lane = (i>>3)&63, ks = (i>>9)&3, rt = (i>>11)&7, wv = (i>>14)&3;
  int row = wv*128 + rt*16 + (lane&15);
  int c   = ks*32 + ((lane>>4)&3)*8 + j;
  int s = row*C_ + c;
  float v;
  if (s < 8192)       v = f32 ? ((const float*)cvw)[s]        : b2f(((const bf16*)cvw)[s]);
  else if (s < 40960) v = f32 ? ((const float*)csw)[s-8192]   : b2f(((const bf16*)csw)[s-8192]);
  else                v = f32 ? ((const float*)caw)[s-40960]  : b2f(((const bf16*)caw)[s-40960]);
  WallF[i] = __float2bfloat16(v);
}

// ---------- K1: L2 norm -> xnF (k_gemm B-frags) and xnG (k_vlad B-frags), both coalesced ----------
__global__ __launch_bounds__(256) void k_norm(const void* __restrict__ x,
                                              bf16* __restrict__ xnF,
                                              bf16* __restrict__ xnG){
  __shared__ float sred[2][128];
  __shared__ __align__(16) unsigned short tile[128][136];   // 34816 B, 16B-aligned rows
  int f32 = is_f32((const unsigned short*)x);
  int bi = blockIdx.x;
  int n = bi / (P_/128), tb = bi % (P_/128);
  int p0 = tb*128;
  int t = threadIdx.x, px = t&127, chh = t>>7, c0 = chh*64;

  float vals[64];
  float ss = 0.f;
  if (f32){
    const float* xb = (const float*)x + ((size_t)n*C_ + c0)*P_ + p0 + px;
    #pragma unroll
    for (int j=0;j<64;++j){ float v = xb[(size_t)j*P_]; vals[j] = v; ss += v*v; }
  } else {
    const unsigned short* xb = (const unsigned short*)x + ((size_t)n*C_ + c0)*P_ + p0 + px;
    #pragma unroll
    for (int j=0;j<64;++j){ float v = u2f(xb[(size_t)j*P_]); vals[j] = v; ss += v*v; }
  }
  sred[chh][px] = ss;
  __syncthreads();
  float invn = 1.f / fmaxf(sqrtf(sred[0][px] + sred[1][px]), 1e-12f);
  unsigned short nv[64];
  #pragma unroll
  for (int j=0;j<64;++j) nv[j] = f2u(vals[j]*invn);

  // ---- phase A: tile[c][px] ----
  #pragma unroll
  for (int j=0;j<64;++j) tile[c0+j][px] = nv[j];
  __syncthreads();
  // emit xnG (chunk ch = tb>>1 covers 256 px; this block is half hb)
  {
    int ch = tb>>1, hb = tb&1;
    size_t gbase = ((size_t)(n*CH_ + ch)*8 + hb*4)*512;
    u16x8* out = (u16x8*)xnG;
    #pragma unroll
    for (int it=0;it<8;++it){
      int o2 = t + it*256;
      int lane = o2&63, half = (o2>>6)&1, wvv = (o2>>7)&3, ksl = (o2>>9)&3;
      int c  = wvv*32 + half*16 + (lane&15);
      int pl = ksl*32 + ((lane>>4)&3)*8;
      out[gbase + o2] = *(const u16x8*)&tile[c][pl];
    }
  }
  __syncthreads();
  // ---- phase B: reuse tile as [px][c] ----
  #pragma unroll
  for (int j8=0;j8<8;++j8)
    *(u16x8*)&tile[px][c0 + j8*8] = *(const u16x8*)&nv[j8*8];
  __syncthreads();
  // emit xnF (4 gemm-tiles pb = tb*4 + pbl)
  {
    size_t fbase = (size_t)(n*NB_ + tb*4)*512;
    u16x8* out = (u16x8*)xnF;
    #pragma unroll
    for (int it=0;it<8;++it){
      int o = t + it*256;
      int lane = o&63, half = (o>>6)&1, ks = (o>>7)&3, pbl = (o>>9)&3;
      int pxr = pbl*32 + half*16 + (lane&15);
      int cc  = ks*32 + ((lane>>4)&3)*8;
      out[fbase + o] = *(const u16x8*)&tile[pxr][cc];
    }
  }
}

// ---------- K2: fused 512-row MFMA GEMM + vectorized softmax + MFMA region sums ----------
// grid (NB_=72, N_=32), 4 waves. Wave w owns rows [w*128, w*128+128).
// ldsU layout (k-major, [320][40] u16, 80B rows, conflict-free b128 at stride-20dw):
//   rows 0..63   = score row k
//   rows 64+s*64+k = shadow s of cluster k   (s-major so softmax reads are per-row vectors)
// appS overlays rows 0..191 AFTER softmax (app logits held packed in regs until then).
__global__ __launch_bounds__(256, 4) void k_gemm(const bf16* __restrict__ WallF,
                                                 const bf16* __restrict__ xnF,
                                                 unsigned short* __restrict__ a,
                                                 float* __restrict__ sal){
  __shared__ __align__(16) unsigned short ldsU[320][40];    // 25600 B
  unsigned short (*appS)[40] = ldsU;                        // overlay rows 0..191
  int n = blockIdx.y, pb = blockIdx.x;
  int p0 = pb*32;
  int t = threadIdx.x, wv = t>>6, l = t&63;
  int mrow = l&15, quad = l>>4;

  const bf16* Af = WallF + ((size_t)(wv*8)*4)*512 + l*8;   // + (rt*4+ks)*512
  const bf16* Bf = xnF + (size_t)(n*NB_ + pb)*4096 + l*8;  // + (ks*2+half)*512

  f32x4 acc[8][2];
  #pragma unroll
  for (int rt=0;rt<8;++rt){ acc[rt][0] = (f32x4){0,0,0,0}; acc[rt][1] = (f32x4){0,0,0,0}; }

  #pragma unroll
  for (int ks=0;ks<4;++ks){
    bf16x8 b0 = *(const bf16x8*)(Bf + (ks*2+0)*512);
    bf16x8 b1 = *(const bf16x8*)(Bf + (ks*2+1)*512);
    #pragma unroll
    for (int rt=0;rt<8;++rt){
      bf16x8 af = *(const bf16x8*)(Af + (rt*4+ks)*512);
      acc[rt][0] = __builtin_amdgcn_mfma_f32_16x16x32_bf16(af, b0, acc[rt][0], 0,0,0);
      acc[rt][1] = __builtin_amdgcn_mfma_f32_16x16x32_bf16(af, b1, acc[rt][1], 0,0,0);
    }
  }

  // C/D: col = lane&15, row = quad*4 + reg.
  // scores/shadows -> ldsU (k-major); app rows -> packed bf16 regs (written after softmax).
  unsigned appPk[8][2][2];
  #pragma unroll
  for (int rt=0;rt<8;++rt){
    int row0 = wv*128 + rt*16;
    if (row0 < 64){
      #pragma unroll
      for (int ct=0;ct<2;++ct)
        #pragma unroll
        for (int r=0;r<4;++r)
          ldsU[row0 + quad*4 + r][ct*16 + mrow] = f2u(acc[rt][ct][r]);
    } else if (row0 < 320){
      #pragma unroll
      for (int ct=0;ct<2;++ct)
        #pragma unroll
        for (int r=0;r<4;++r){
          int sr = row0 + quad*4 + r - 64;                  // = k*4 + s
          ldsU[64 + (sr&3)*64 + (sr>>2)][ct*16 + mrow] = f2u(acc[rt][ct][r]);
        }
    } else {
      #pragma unroll
      for (int ct=0;ct<2;++ct){
        appPk[rt][ct][0] = (unsigned)f2u(fmaxf(acc[rt][ct][0],0.f))
                         | ((unsigned)f2u(fmaxf(acc[rt][ct][1],0.f)) << 16);
        appPk[rt][ct][1] = (unsigned)f2u(fmaxf(acc[rt][ct][2],0.f))
                         | ((unsigned)f2u(fmaxf(acc[rt][ct][3],0.f)) << 16);
      }
    }
  }
  __syncthreads();

  // ---- softmax: lane = k, wave wv = pixel-group (8 px). 5 x ds_read_b128, no conflicts.
  // |logit| <= ~1.2 (normalized x, 0.1-scaled weights) -> max-subtraction safely dropped.
  {
    int pg = wv;
    u16x8 s8  = *(const u16x8*)&ldsU[l      ][pg*8];
    u16x8 h0v = *(const u16x8*)&ldsU[64  + l][pg*8];
    u16x8 h1v = *(const u16x8*)&ldsU[128 + l][pg*8];
    u16x8 h2v = *(const u16x8*)&ldsU[192 + l][pg*8];
    u16x8 h3v = *(const u16x8*)&ldsU[256 + l][pg*8];
    float ez[8], Zr[8];
    #pragma unroll
    for (int j=0;j<8;++j){ ez[j] = __expf(u2f((unsigned short)s8[j])); Zr[j] = ez[j]; }
    #pragma unroll
    for (int st=1; st<64; st<<=1){
      #pragma unroll
      for (int j=0;j<8;++j) Zr[j] += __shfl_xor(Zr[j], st);
    }
    size_t tile = (size_t)n*NB_ + pb;
    #pragma unroll
    for (int j=0;j<8;++j){
      float e0 = ez[j];
      float den = e0 + __expf(u2f((unsigned short)h0v[j]))
                     + __expf(u2f((unsigned short)h1v[j]))
                     + __expf(u2f((unsigned short)h2v[j]))
                     + __expf(u2f((unsigned short)h3v[j]));
      // a = (e0/Z) * (e0/den); coalesced 128B row store
      a[tile*2048 + (size_t)(pg*8+j)*64 + l] = f2u(__fdividef(e0*e0, Zr[j]*den));
    }
  }
  __syncthreads();   // all ldsU reads done; safe to overlay appS

  // ---- app rows (relu'd bf16, from regs) -> appS ----
  #pragma unroll
  for (int rt=0;rt<8;++rt){
    int row0 = wv*128 + rt*16;
    if (row0 >= 320){
      int ar0 = row0 - 320 + quad*4;
      #pragma unroll
      for (int ct=0;ct<2;++ct){
        appS[ar0+0][ct*16+mrow] = (unsigned short)(appPk[rt][ct][0] & 0xffff);
        appS[ar0+1][ct*16+mrow] = (unsigned short)(appPk[rt][ct][0] >> 16);
        appS[ar0+2][ct*16+mrow] = (unsigned short)(appPk[rt][ct][1] & 0xffff);
        appS[ar0+3][ct*16+mrow] = (unsigned short)(appPk[rt][ct][1] >> 16);
      }
    }
  }
  __syncthreads();

  // ---- region sums via MFMA: sal[k][r] += sum_p app[k][p] * M[r][p] ----
  // B-frag: col = lane&15 = region r (tile0: r, tile1: 16+r), k-dim px = quad*8+j.
  bf16x8 bm0, bm1;
  #pragma unroll
  for (int j=0;j<8;++j){
    int p = p0 + quad*8 + j;
    int h = p/48, wc = p - h*48;
    bm0[j] = (short)region_bit(mrow,      h, wc);
    bm1[j] = (short)region_bit(16 + mrow, h, wc);
  }
  f32x4 racc[3][2];
  #pragma unroll
  for (int i=0;i<3;++i){ racc[i][0] = (f32x4){0,0,0,0}; racc[i][1] = (f32x4){0,0,0,0}; }
  #pragma unroll
  for (int i=0;i<3;++i){
    int rt = wv*3 + i;                                     // 12 row-tiles over 4 waves
    bf16x8 af = *(const bf16x8*)&appS[rt*16 + mrow][quad*8];
    racc[i][0] = __builtin_amdgcn_mfma_f32_16x16x32_bf16(af, bm0, racc[i][0], 0,0,0);
    racc[i][1] = __builtin_amdgcn_mfma_f32_16x16x32_bf16(af, bm1, racc[i][1], 0,0,0);
  }
  // D: col = lane&15 = r, row = quad*4+reg = app row. Store only level-valid columns.
  size_t salb = (size_t)n*(K_*R_);
  #pragma unroll
  for (int i=0;i<3;++i){
    int rt = wv*3 + i;
    int kb = rt*16 + quad*4;
    if (rt < 4){                       // level0 rows 0..63: region col 0 only
      if (mrow == 0){
        #pragma unroll
        for (int r=0;r<4;++r) atomicAdd(&sal[salb + (size_t)(kb+r)*R_], racc[i][0][r]);
      }
    } else if (rt < 8){                // level1 rows 64..127: cols 1..4
      if (mrow >= 1 && mrow <= 4){
        #pragma unroll
        for (int r=0;r<4;++r) atomicAdd(&sal[salb + (size_t)(kb+r-64)*R_ + mrow], racc[i][0][r]);
      }
    } else {                           // level2 rows 128..191: cols 5..20
      if (mrow >= 5){
        #pragma unroll
        for (int r=0;r<4;++r) atomicAdd(&sal[salb + (size_t)(kb+r-128)*R_ + mrow], racc[i][0][r]);
      } else {
        #pragma unroll
        for (int r=0;r<4;++r) atomicAdd(&sal[salb + (size_t)(kb+r-128)*R_ + 16 + mrow], racc[i][1][r]);
      }
    }
  }
}

// ---------- K4: vlad partials via MFMA. Block = (chunk of 256 px, n). ----------
__global__ __launch_bounds__(256) void k_vlad(const bf16* __restrict__ xnG,
                                              const unsigned short* __restrict__ a,
                                              const float* __restrict__ sal,
                                              float* __restrict__ vladPart,
                                              float* __restrict__ sumawPart){
  __shared__ float s_sal[K_][R_];                    // 5376 B
  __shared__ __align__(16) unsigned short awL[8][K_][40];  // 40960 B
  __shared__ float s_part[8][K_];                    // 2048 B
  int chunk = blockIdx.x, n = blockIdx.y, t = threadIdx.x;
  int p0 = chunk*256;
  for (int i=t;i<K_*R_;i+=256) ((float*)s_sal)[i] = sal[(size_t)n*K_*R_ + i];
  __syncthreads();

  #pragma unroll
  for (int pg=0;pg<2;++pg){
    int pxl = (t & 127) + pg*128, khalf = t>>7;
    int pbl = pxl>>5, px = pxl&31;
    int p = p0 + pxl;
    int h = p/48, wc = p - h*48;
    bool h1[2], w1[2], h2[4], w2[4];
    #pragma unroll
    for (int i=0;i<2;++i){ h1[i] = (h>=16*i)&&(h<16*i+32); w1[i] = (wc>=16*i)&&(wc<16*i+32); }
    #pragma unroll
    for (int i=0;i<4;++i){ h2[i] = (h>=10*i-1)&&(h<10*i+19); w2[i] = (wc>=10*i-1)&&(wc<10*i+19); }
    const unsigned short* at = a + ((size_t)((n*NB_ + chunk*8 + pbl)*32 + px))*K_ + khalf*32;
    u16x8 av[4];
    #pragma unroll
    for (int q=0;q<4;++q) av[q] = *(const u16x8*)(at + q*8);
    #pragma unroll
    for (int kk=0;kk<32;++kk){
      int k = khalf*32 + kk;
      float w = s_sal[k][0];
      #pragma unroll
      for (int i=0;i<2;++i) if (h1[i])
        #pragma unroll
        for (int j=0;j<2;++j) if (w1[j]) w += s_sal[k][1+2*i+j];
      #pragma unroll
      for (int i=0;i<4;++i) if (h2[i])
        #pragma unroll
        for (int j=0;j<4;++j) if (w2[j]) w += s_sal[k][5+4*i+j];
      awL[pbl][k][px] = f2u(u2f(av[kk>>3][kk&7]) * w);
    }
  }
  __syncthreads();
  {
    int k = t&63, qr0 = t>>6;
    #pragma unroll
    for (int qq=0;qq<2;++qq){
      int qr = qr0 + qq*4;
      float s = 0.f;
      #pragma unroll 8
      for (int j=0;j<32;++j) s += u2f(awL[qr][k][j]);
      s_part[qr][k] = s;
    }
  }
  __syncthreads();

  int wv = t>>6, l = t&63, mrow = l&15, quad = l>>4;
  f32x4 acc[4][2];
  #pragma unroll
  for (int mt=0;mt<4;++mt){ acc[mt][0] = (f32x4){0,0,0,0}; acc[mt][1] = (f32x4){0,0,0,0}; }
  const bf16* Gf = xnG + (size_t)(n*CH_ + chunk)*32768 + l*8;  // + ((ks*4+wv)*2+half)*512
  #pragma unroll
  for (int ks=0;ks<8;++ks){
    bf16x8 b0 = *(const bf16x8*)(Gf + ((ks*4+wv)*2+0)*512);
    bf16x8 b1 = *(const bf16x8*)(Gf + ((ks*4+wv)*2+1)*512);
    #pragma unroll
    for (int mt=0;mt<4;++mt){
      bf16x8 af = *(const bf16x8*)((const bf16*)&awL[ks][mt*16 + mrow][quad*8]);
      acc[mt][0] = __builtin_amdgcn_mfma_f32_16x16x32_bf16(af, b0, acc[mt][0], 0,0,0);
      acc[mt][1] = __builtin_amdgcn_mfma_f32_16x16x32_bf16(af, b1, acc[mt][1], 0,0,0);
    }
  }
  float* vp = vladPart + ((size_t)(n*CH_ + chunk))*(K_*C_);
  #pragma unroll
  for (int mt=0;mt<4;++mt){
    #pragma unroll
    for (int ct=0;ct<2;++ct){
      int c = wv*32 + ct*16 + mrow;
      #pragma unroll
      for (int r=0;r<4;++r){
        int k = mt*16 + quad*4 + r;
        vp[k*C_ + c] = acc[mt][ct][r];
      }
    }
  }
  if (t < K_){
    float s = 0.f;
    #pragma unroll
    for (int qr=0;qr<8;++qr) s += s_part[qr][t];
    sumawPart[((size_t)n*CH_ + chunk)*K_ + t] = s;
  }
}

// ---------- K5: parallel chunk reduce + centroid term -> vlad ----------
__global__ __launch_bounds__(256) void k_vred(const float* __restrict__ vladPart,
                                              const float* __restrict__ sumawPart,
                                              const void* __restrict__ cen,
                                              const void* __restrict__ x,
                                              float* __restrict__ vlad){
  int f32 = is_f32((const unsigned short*)x);
  int tid = blockIdx.x*256 + threadIdx.x;       // < N_*K_*C_ = 262144
  int n = tid >> 13;
  int i = tid & 8191;
  int k = i >> 7;
  const float* vp = vladPart + (size_t)n*CH_*(K_*C_) + i;
  float s = 0.f;
  #pragma unroll
  for (int ch=0;ch<CH_;++ch) s += vp[(size_t)ch*(K_*C_)];
  float sw = 0.f;
  #pragma unroll
  for (int ch=0;ch<CH_;++ch) sw += sumawPart[((size_t)n*CH_ + ch)*K_ + k];
  float cv = f32 ? ((const float*)cen)[i] : b2f(((const bf16*)cen)[i]);
  vlad[tid] = s - cv*sw;
}

// ---------- K6: intra-norm * cluster_weights, global L2 norm, store ----------
__global__ __launch_bounds__(256) void k_final(const float* __restrict__ vlad,
                                               const void* __restrict__ clw,
                                               const void* __restrict__ x,
                                               void* __restrict__ out){
  __shared__ float s_v[K_*C_];
  __shared__ float s_ssk[K_];
  __shared__ float s_scale[K_];
  __shared__ float s_gs;
  int n = blockIdx.x, t = threadIdx.x;
  int f32 = is_f32((const unsigned short*)x);
  const float* vp = vlad + (size_t)n*K_*C_;
  for (int i=t;i<K_*C_;i+=256) s_v[i] = vp[i];
  __syncthreads();
  int k = t >> 2, q = t & 3;
  float ss = 0.f;
  for (int mm=0;mm<32;++mm){ float v = s_v[k*C_ + q + 4*mm]; ss += v*v; }
  ss += __shfl_down(ss, 2);
  ss += __shfl_down(ss, 1);
  if (q == 0) s_ssk[k] = ss;
  __syncthreads();
  if (t < K_){
    float cw = f32 ? ((const float*)clw)[t] : b2f(((const bf16*)clw)[t]);
    s_scale[t] = cw / fmaxf(sqrtf(s_ssk[t]), 1e-12f);
  }
  __syncthreads();
  if (t == 0){
    float gss = 0.f;
    for (int kk=0;kk<K_;++kk) gss += s_ssk[kk]*s_scale[kk]*s_scale[kk];
    s_gs = 1.f / fmaxf(sqrtf(gss), 1e-12f);
  }
  __syncthreads();
  float gsc = s_gs;
  if (f32){
    float* op = (float*)out + (size_t)n*K_*C_;
    for (int i=t;i<K_*C_;i+=256) op[i] = s_v[i]*s_scale[i>>7]*gsc;
  } else {
    bf16* op = (bf16*)out + (size_t)n*K_*C_;
    for (int i=t;i<K_*C_;i+=256) op[i] = __float2bfloat16(s_v[i]*s_scale[i>>7]*gsc);
  }
}

extern "C" void kernel_launch(void* const* d_in, const int* in_sizes, int n_in,
                              void* d_out, int out_size, void* d_ws, size_t ws_size,
                              hipStream_t stream){
  const void* x   = d_in[0];
  const void* cen = d_in[1];
  const void* cvw = d_in[2];
  const void* csw = d_in[3];
  const void* caw = d_in[4];
  const void* clw = d_in[5];

  char* ws = (char*)d_ws;
  bf16* WallF = (bf16*)ws;             ws += (size_t)M_*C_*2;        // 128 KB
  bf16* xnF   = (bf16*)ws;             ws += (size_t)N_*P_*C_*2;     // 18.87 MB
  bf16* xnG   = (bf16*)ws;             ws += (size_t)N_*C_*P_*2;     // 18.87 MB
  char* aBuf  = ws;                    ws += (size_t)N_*K_*P_*2;     // 9.44 MB
  unsigned short* a = (unsigned short*)aBuf;   // dead after k_vlad
  float* vlad = (float*)aBuf;                  // overlay: written by k_vred (1 MB)
  float* sal  = (float*)ws;            ws += (size_t)N_*K_*R_*4;     // 0.17 MB
  char* un = ws;
  float* vladPart  = (float*)un;
  float* sumawPart = (float*)(un + (size_t)N_*CH_*K_*C_*4);
  ws += (size_t)N_*CH_*K_*C_*4 + (size_t)N_*CH_*K_*4;                // 9.5 MB

  hipMemsetAsync(sal, 0, (size_t)N_*K_*R_*4, stream);                // atomic accumulation target
  k_wall  <<<dim3(M_*C_/256),       256, 0, stream>>>(cvw, csw, caw, x, WallF);
  k_norm  <<<dim3(N_*P_/128),       256, 0, stream>>>(x, xnF, xnG);
  k_gemm  <<<dim3(NB_, N_),         256, 0, stream>>>(WallF, xnF, a, sal);
  k_vlad  <<<dim3(CH_, N_),         256, 0, stream>>>(xnG, a, sal, vladPart, sumawPart);
  k_vred  <<<dim3(N_*K_*C_/256),    256, 0, stream>>>(vladPart, sumawPart, cen, x, vlad);
  k_final <<<dim3(N_),              256, 0, stream>>>(vlad, clw, x, d_out);
}

// Round 2
// 189.292 us; speedup vs baseline: 1.1410x; 1.1410x over previous
//
#include <hip/hip_runtime.h>
#include <hip/hip_bf16.h>

#define N_ 32
#define C_ 128
#define H_ 48
#define W_ 48
#define P_ (H_*W_)   // 2304
#define K_ 64
#define S_ 4
#define L_ 3
#define R_ 21
#define NB_ 72       // P_/32 pixel tiles per image
#define M_ 512       // total logit rows
#define CH_ 9        // vlad chunks (256 px each)

typedef __hip_bfloat16 bf16;
typedef __attribute__((ext_vector_type(8))) short   bf16x8;
typedef __attribute__((ext_vector_type(8))) unsigned short u16x8;
typedef __attribute__((ext_vector_type(4))) float   f32x4;

__device__ __forceinline__ float b2f(bf16 v){ return __bfloat162float(v); }
__device__ __forceinline__ float u2f(unsigned short u){
  union { unsigned i; float f; } v; v.i = ((unsigned)u) << 16; return v.f;
}
__device__ __forceinline__ unsigned short f2u(float f){
  bf16 h = __float2bfloat16(f);
  return *(unsigned short*)&h;
}

// wave-uniform dtype probe: 1 if x is fp32, 0 if bf16 (reads fixed 1024-elem window).
__device__ __forceinline__ int is_f32(const unsigned short* __restrict__ xb){
  int lane = threadIdx.x & 63;
  int w = 0;
  #pragma unroll
  for (int i=0;i<16;++i){
    int e = (xb[lane*16 + i] >> 7) & 0xFF;
    w += (e >= 0x8E) ? 1 : 0;
  }
  unsigned long long b = __ballot(w > 0);
  return __popcll(b) > 32;
}

// region membership for global region index r (0..20) at pixel (h,w); bf16 1.0/0.0 bits
__device__ __forceinline__ unsigned short region_bit(int r, int h, int w){
  bool m;
  if (r == 0){
    m = true;
  } else if (r < 5){
    int q = r-1, i = q>>1, j = q&1;
    m = (h>=16*i)&&(h<16*i+32)&&(w>=16*j)&&(w<16*j+32);
  } else if (r < 21){
    int q = r-5, i = q>>2, j = q&3;
    m = (h>=10*i-1)&&(h<10*i+19)&&(w>=10*j-1)&&(w<10*j+19);
  } else {
    m = false;
  }
  return m ? (unsigned short)0x3F80 : (unsigned short)0;
}

// ---------- K0: build WallF in MFMA-fragment order ----------
// frag f = (((wv*8+rt)*4+ks)*64 + lane)*8 + j  <-  row = wv*128+rt*16+(lane&15),
// c = ks*32 + ((lane>>4)&3)*8 + j. Rows: 0-63 score, 64-319 shadow, 320-511 app.
__global__ __launch_bounds__(256) void k_wall(const void* __restrict__ cvw, const void* __restrict__ csw,
                                              const void* __restrict__ caw, const void* __restrict__ x,
                                              bf16* __restrict__ WallF){
  int f32 = is_f32((const unsigned short*)x);
  int i = blockIdx.x*256 + threadIdx.x;          // 0..65535
  int j = i&7, lane = (i>>3)&63, ks = (i>>9)&3, rt = (i>>11)&7, wv = (i>>14)&3;
  int row = wv*128 + rt*16 + (lane&15);
  int c   = ks*32 + ((lane>>4)&3)*8 + j;
  int s = row*C_ + c;
  float v;
  if (s < 8192)       v = f32 ? ((const float*)cvw)[s]        : b2f(((const bf16*)cvw)[s]);
  else if (s < 40960) v = f32 ? ((const float*)csw)[s-8192]   : b2f(((const bf16*)csw)[s-8192]);
  else                v = f32 ? ((const float*)caw)[s-40960]  : b2f(((const bf16*)caw)[s-40960]);
  WallF[i] = __float2bfloat16(v);
}

// ---------- K1: L2 norm -> xnF (k_gemm B-frags) and xnG (k_vlad B-frags), both coalesced ----------
__global__ __launch_bounds__(256) void k_norm(const void* __restrict__ x,
                                              bf16* __restrict__ xnF,
                                              bf16* __restrict__ xnG){
  __shared__ float sred[2][128];
  __shared__ __align__(16) unsigned short tile[128][136];   // 34816 B, 16B-aligned rows
  int f32 = is_f32((const unsigned short*)x);
  int bi = blockIdx.x;
  int n = bi / (P_/128), tb = bi % (P_/128);
  int p0 = tb*128;
  int t = threadIdx.x, px = t&127, chh = t>>7, c0 = chh*64;

  float vals[64];
  float ss = 0.f;
  if (f32){
    const float* xb = (const float*)x + ((size_t)n*C_ + c0)*P_ + p0 + px;
    #pragma unroll
    for (int j=0;j<64;++j){ float v = xb[(size_t)j*P_]; vals[j] = v; ss += v*v; }
  } else {
    const unsigned short* xb = (const unsigned short*)x + ((size_t)n*C_ + c0)*P_ + p0 + px;
    #pragma unroll
    for (int j=0;j<64;++j){ float v = u2f(xb[(size_t)j*P_]); vals[j] = v; ss += v*v; }
  }
  sred[chh][px] = ss;
  __syncthreads();
  float invn = 1.f / fmaxf(sqrtf(sred[0][px] + sred[1][px]), 1e-12f);
  unsigned short nv[64];
  #pragma unroll
  for (int j=0;j<64;++j) nv[j] = f2u(vals[j]*invn);

  // ---- phase A: tile[c][px] ----
  #pragma unroll
  for (int j=0;j<64;++j) tile[c0+j][px] = nv[j];
  __syncthreads();
  // emit xnG (chunk ch = tb>>1 covers 256 px; this block is half hb)
  {
    int ch = tb>>1, hb = tb&1;
    size_t gbase = ((size_t)(n*CH_ + ch)*8 + hb*4)*512;
    u16x8* out = (u16x8*)xnG;
    #pragma unroll
    for (int it=0;it<8;++it){
      int o2 = t + it*256;
      int lane = o2&63, half = (o2>>6)&1, wvv = (o2>>7)&3, ksl = (o2>>9)&3;
      int c  = wvv*32 + half*16 + (lane&15);
      int pl = ksl*32 + ((lane>>4)&3)*8;
      out[gbase + o2] = *(const u16x8*)&tile[c][pl];
    }
  }
  __syncthreads();
  // ---- phase B: reuse tile as [px][c] ----
  #pragma unroll
  for (int j8=0;j8<8;++j8)
    *(u16x8*)&tile[px][c0 + j8*8] = *(const u16x8*)&nv[j8*8];
  __syncthreads();
  // emit xnF (4 gemm-tiles pb = tb*4 + pbl)
  {
    size_t fbase = (size_t)(n*NB_ + tb*4)*512;
    u16x8* out = (u16x8*)xnF;
    #pragma unroll
    for (int it=0;it<8;++it){
      int o = t + it*256;
      int lane = o&63, half = (o>>6)&1, ks = (o>>7)&3, pbl = (o>>9)&3;
      int pxr = pbl*32 + half*16 + (lane&15);
      int cc  = ks*32 + ((lane>>4)&3)*8;
      out[fbase + o] = *(const u16x8*)&tile[pxr][cc];
    }
  }
}

// ---------- K2: fused 512-row MFMA GEMM + vectorized softmax + MFMA region sums ----------
// grid (NB_=72, N_=32), 4 waves. Wave w owns rows [w*128, w*128+128).
// ldsU layout (k-major, [320][40] u16, 80B rows, conflict-free b128 at stride-20dw):
//   rows 0..63   = score row k
//   rows 64+s*64+k = shadow s of cluster k   (s-major so softmax reads are per-row vectors)
// appS overlays rows 0..191 AFTER softmax (app logits held packed in regs until then).
// Region partials: plain per-tile stores to salPart (contention-free), reduced by k_salred.
__global__ __launch_bounds__(256, 4) void k_gemm(const bf16* __restrict__ WallF,
                                                 const bf16* __restrict__ xnF,
                                                 unsigned short* __restrict__ a,
                                                 float* __restrict__ salPart){
  __shared__ __align__(16) unsigned short ldsU[320][40];    // 25600 B
  unsigned short (*appS)[40] = ldsU;                        // overlay rows 0..191
  int n = blockIdx.y, pb = blockIdx.x;
  int p0 = pb*32;
  int t = threadIdx.x, wv = t>>6, l = t&63;
  int mrow = l&15, quad = l>>4;

  const bf16* Af = WallF + ((size_t)(wv*8)*4)*512 + l*8;   // + (rt*4+ks)*512
  const bf16* Bf = xnF + (size_t)(n*NB_ + pb)*4096 + l*8;  // + (ks*2+half)*512

  f32x4 acc[8][2];
  #pragma unroll
  for (int rt=0;rt<8;++rt){ acc[rt][0] = (f32x4){0,0,0,0}; acc[rt][1] = (f32x4){0,0,0,0}; }

  #pragma unroll
  for (int ks=0;ks<4;++ks){
    bf16x8 b0 = *(const bf16x8*)(Bf + (ks*2+0)*512);
    bf16x8 b1 = *(const bf16x8*)(Bf + (ks*2+1)*512);
    #pragma unroll
    for (int rt=0;rt<8;++rt){
      bf16x8 af = *(const bf16x8*)(Af + (rt*4+ks)*512);
      acc[rt][0] = __builtin_amdgcn_mfma_f32_16x16x32_bf16(af, b0, acc[rt][0], 0,0,0);
      acc[rt][1] = __builtin_amdgcn_mfma_f32_16x16x32_bf16(af, b1, acc[rt][1], 0,0,0);
    }
  }

  // C/D: col = lane&15, row = quad*4 + reg.
  // scores/shadows -> ldsU (k-major); app rows -> packed bf16 regs (written after softmax).
  unsigned appPk[8][2][2];
  #pragma unroll
  for (int rt=0;rt<8;++rt){
    int row0 = wv*128 + rt*16;
    if (row0 < 64){
      #pragma unroll
      for (int ct=0;ct<2;++ct)
        #pragma unroll
        for (int r=0;r<4;++r)
          ldsU[row0 + quad*4 + r][ct*16 + mrow] = f2u(acc[rt][ct][r]);
    } else if (row0 < 320){
      #pragma unroll
      for (int ct=0;ct<2;++ct)
        #pragma unroll
        for (int r=0;r<4;++r){
          int sr = row0 + quad*4 + r - 64;                  // = k*4 + s
          ldsU[64 + (sr&3)*64 + (sr>>2)][ct*16 + mrow] = f2u(acc[rt][ct][r]);
        }
    } else {
      #pragma unroll
      for (int ct=0;ct<2;++ct){
        appPk[rt][ct][0] = (unsigned)f2u(fmaxf(acc[rt][ct][0],0.f))
                         | ((unsigned)f2u(fmaxf(acc[rt][ct][1],0.f)) << 16);
        appPk[rt][ct][1] = (unsigned)f2u(fmaxf(acc[rt][ct][2],0.f))
                         | ((unsigned)f2u(fmaxf(acc[rt][ct][3],0.f)) << 16);
      }
    }
  }
  __syncthreads();

  // ---- softmax: lane = k, wave wv = pixel-group (8 px). 5 x ds_read_b128, no conflicts.
  // |logit| <= ~1.2 (normalized x, 0.1-scaled weights) -> max-subtraction safely dropped.
  {
    int pg = wv;
    u16x8 s8  = *(const u16x8*)&ldsU[l      ][pg*8];
    u16x8 h0v = *(const u16x8*)&ldsU[64  + l][pg*8];
    u16x8 h1v = *(const u16x8*)&ldsU[128 + l][pg*8];
    u16x8 h2v = *(const u16x8*)&ldsU[192 + l][pg*8];
    u16x8 h3v = *(const u16x8*)&ldsU[256 + l][pg*8];
    float ez[8], Zr[8];
    #pragma unroll
    for (int j=0;j<8;++j){ ez[j] = __expf(u2f((unsigned short)s8[j])); Zr[j] = ez[j]; }
    #pragma unroll
    for (int st=1; st<64; st<<=1){
      #pragma unroll
      for (int j=0;j<8;++j) Zr[j] += __shfl_xor(Zr[j], st);
    }
    size_t tile = (size_t)n*NB_ + pb;
    #pragma unroll
    for (int j=0;j<8;++j){
      float e0 = ez[j];
      float den = e0 + __expf(u2f((unsigned short)h0v[j]))
                     + __expf(u2f((unsigned short)h1v[j]))
                     + __expf(u2f((unsigned short)h2v[j]))
                     + __expf(u2f((unsigned short)h3v[j]));
      // a = (e0/Z) * (e0/den); coalesced 128B row store
      a[tile*2048 + (size_t)(pg*8+j)*64 + l] = f2u(__fdividef(e0*e0, Zr[j]*den));
    }
  }
  __syncthreads();   // all ldsU reads done; safe to overlay appS

  // ---- app rows (relu'd bf16, from regs) -> appS ----
  #pragma unroll
  for (int rt=0;rt<8;++rt){
    int row0 = wv*128 + rt*16;
    if (row0 >= 320){
      int ar0 = row0 - 320 + quad*4;
      #pragma unroll
      for (int ct=0;ct<2;++ct){
        appS[ar0+0][ct*16+mrow] = (unsigned short)(appPk[rt][ct][0] & 0xffff);
        appS[ar0+1][ct*16+mrow] = (unsigned short)(appPk[rt][ct][0] >> 16);
        appS[ar0+2][ct*16+mrow] = (unsigned short)(appPk[rt][ct][1] & 0xffff);
        appS[ar0+3][ct*16+mrow] = (unsigned short)(appPk[rt][ct][1] >> 16);
      }
    }
  }
  __syncthreads();

  // ---- region sums via MFMA: salPart[tile][k][r] = sum_p app[k][p] * M[r][p] ----
  // B-frag: col = lane&15 = region r (tile0: r, tile1: 16+r), k-dim px = quad*8+j.
  bf16x8 bm0, bm1;
  #pragma unroll
  for (int j=0;j<8;++j){
    int p = p0 + quad*8 + j;
    int h = p/48, wc = p - h*48;
    bm0[j] = (short)region_bit(mrow,      h, wc);
    bm1[j] = (short)region_bit(16 + mrow, h, wc);
  }
  f32x4 racc[3][2];
  #pragma unroll
  for (int i=0;i<3;++i){ racc[i][0] = (f32x4){0,0,0,0}; racc[i][1] = (f32x4){0,0,0,0}; }
  #pragma unroll
  for (int i=0;i<3;++i){
    int rt = wv*3 + i;                                     // 12 row-tiles over 4 waves
    bf16x8 af = *(const bf16x8*)&appS[rt*16 + mrow][quad*8];
    racc[i][0] = __builtin_amdgcn_mfma_f32_16x16x32_bf16(af, bm0, racc[i][0], 0,0,0);
    racc[i][1] = __builtin_amdgcn_mfma_f32_16x16x32_bf16(af, bm1, racc[i][1], 0,0,0);
  }
  // D: col = lane&15 = r, row = quad*4+reg = app row. Each (k,r) written exactly once.
  {
    size_t tile = (size_t)n*NB_ + pb;
    float* sp = salPart + tile*(K_*R_);
    #pragma unroll
    for (int i=0;i<3;++i){
      int rt = wv*3 + i;
      int kb = rt*16 + quad*4;
      if (rt < 4){                       // level0 rows 0..63: region col 0 only
        if (mrow == 0){
          #pragma unroll
          for (int r=0;r<4;++r) sp[(size_t)(kb+r)*R_] = racc[i][0][r];
        }
      } else if (rt < 8){                // level1 rows 64..127: cols 1..4
        if (mrow >= 1 && mrow <= 4){
          #pragma unroll
          for (int r=0;r<4;++r) sp[(size_t)(kb+r-64)*R_ + mrow] = racc[i][0][r];
        }
      } else {                           // level2 rows 128..191: cols 5..20
        if (mrow >= 5){
          #pragma unroll
          for (int r=0;r<4;++r) sp[(size_t)(kb+r-128)*R_ + mrow] = racc[i][0][r];
        } else {
          #pragma unroll
          for (int r=0;r<4;++r) sp[(size_t)(kb+r-128)*R_ + 16 + mrow] = racc[i][1][r];
        }
      }
    }
  }
}

// ---------- K3: reduce 72 tile partials -> sal[n][k][21] ----------
__global__ __launch_bounds__(256) void k_salred(const float* __restrict__ salPart,
                                                float* __restrict__ sal){
  int tid = blockIdx.x*256 + threadIdx.x;
  if (tid >= N_*K_*R_) return;
  int n = tid / (K_*R_), i = tid - n*(K_*R_);
  const float* sp = salPart + (size_t)n*NB_*(K_*R_) + i;
  float s = 0.f;
  #pragma unroll 8
  for (int b=0;b<NB_;++b) s += sp[(size_t)b*(K_*R_)];
  sal[tid] = s;
}

// ---------- K4: vlad partials via MFMA. Block = (chunk of 256 px, n). ----------
__global__ __launch_bounds__(256) void k_vlad(const bf16* __restrict__ xnG,
                                              const unsigned short* __restrict__ a,
                                              const float* __restrict__ sal,
                                              float* __restrict__ vladPart,
                                              float* __restrict__ sumawPart){
  __shared__ float s_sal[K_][R_];                    // 5376 B
  __shared__ __align__(16) unsigned short awL[8][K_][40];  // 40960 B
  __shared__ float s_part[8][K_];                    // 2048 B
  int chunk = blockIdx.x, n = blockIdx.y, t = threadIdx.x;
  int p0 = chunk*256;
  for (int i=t;i<K_*R_;i+=256) ((float*)s_sal)[i] = sal[(size_t)n*K_*R_ + i];
  __syncthreads();

  #pragma unroll
  for (int pg=0;pg<2;++pg){
    int pxl = (t & 127) + pg*128, khalf = t>>7;
    int pbl = pxl>>5, px = pxl&31;
    int p = p0 + pxl;
    int h = p/48, wc = p - h*48;
    bool h1[2], w1[2], h2[4], w2[4];
    #pragma unroll
    for (int i=0;i<2;++i){ h1[i] = (h>=16*i)&&(h<16*i+32); w1[i] = (wc>=16*i)&&(wc<16*i+32); }
    #pragma unroll
    for (int i=0;i<4;++i){ h2[i] = (h>=10*i-1)&&(h<10*i+19); w2[i] = (wc>=10*i-1)&&(wc<10*i+19); }
    const unsigned short* at = a + ((size_t)((n*NB_ + chunk*8 + pbl)*32 + px))*K_ + khalf*32;
    u16x8 av[4];
    #pragma unroll
    for (int q=0;q<4;++q) av[q] = *(const u16x8*)(at + q*8);
    #pragma unroll
    for (int kk=0;kk<32;++kk){
      int k = khalf*32 + kk;
      float w = s_sal[k][0];
      #pragma unroll
      for (int i=0;i<2;++i) if (h1[i])
        #pragma unroll
        for (int j=0;j<2;++j) if (w1[j]) w += s_sal[k][1+2*i+j];
      #pragma unroll
      for (int i=0;i<4;++i) if (h2[i])
        #pragma unroll
        for (int j=0;j<4;++j) if (w2[j]) w += s_sal[k][5+4*i+j];
      awL[pbl][k][px] = f2u(u2f(av[kk>>3][kk&7]) * w);
    }
  }
  __syncthreads();
  {
    int k = t&63, qr0 = t>>6;
    #pragma unroll
    for (int qq=0;qq<2;++qq){
      int qr = qr0 + qq*4;
      float s = 0.f;
      #pragma unroll 8
      for (int j=0;j<32;++j) s += u2f(awL[qr][k][j]);
      s_part[qr][k] = s;
    }
  }
  __syncthreads();

  int wv = t>>6, l = t&63, mrow = l&15, quad = l>>4;
  f32x4 acc[4][2];
  #pragma unroll
  for (int mt=0;mt<4;++mt){ acc[mt][0] = (f32x4){0,0,0,0}; acc[mt][1] = (f32x4){0,0,0,0}; }
  const bf16* Gf = xnG + (size_t)(n*CH_ + chunk)*32768 + l*8;  // + ((ks*4+wv)*2+half)*512
  #pragma unroll
  for (int ks=0;ks<8;++ks){
    bf16x8 b0 = *(const bf16x8*)(Gf + ((ks*4+wv)*2+0)*512);
    bf16x8 b1 = *(const bf16x8*)(Gf + ((ks*4+wv)*2+1)*512);
    #pragma unroll
    for (int mt=0;mt<4;++mt){
      bf16x8 af = *(const bf16x8*)((const bf16*)&awL[ks][mt*16 + mrow][quad*8]);
      acc[mt][0] = __builtin_amdgcn_mfma_f32_16x16x32_bf16(af, b0, acc[mt][0], 0,0,0);
      acc[mt][1] = __builtin_amdgcn_mfma_f32_16x16x32_bf16(af, b1, acc[mt][1], 0,0,0);
    }
  }
  float* vp = vladPart + ((size_t)(n*CH_ + chunk))*(K_*C_);
  #pragma unroll
  for (int mt=0;mt<4;++mt){
    #pragma unroll
    for (int ct=0;ct<2;++ct){
      int c = wv*32 + ct*16 + mrow;
      #pragma unroll
      for (int r=0;r<4;++r){
        int k = mt*16 + quad*4 + r;
        vp[k*C_ + c] = acc[mt][ct][r];
      }
    }
  }
  if (t < K_){
    float s = 0.f;
    #pragma unroll
    for (int qr=0;qr<8;++qr) s += s_part[qr][t];
    sumawPart[((size_t)n*CH_ + chunk)*K_ + t] = s;
  }
}

// ---------- K5: parallel chunk reduce + centroid term -> vlad ----------
__global__ __launch_bounds__(256) void k_vred(const float* __restrict__ vladPart,
                                              const float* __restrict__ sumawPart,
                                              const void* __restrict__ cen,
                                              const void* __restrict__ x,
                                              float* __restrict__ vlad){
  int f32 = is_f32((const unsigned short*)x);
  int tid = blockIdx.x*256 + threadIdx.x;       // < N_*K_*C_ = 262144
  int n = tid >> 13;
  int i = tid & 8191;
  int k = i >> 7;
  const float* vp = vladPart + (size_t)n*CH_*(K_*C_) + i;
  float s = 0.f;
  #pragma unroll
  for (int ch=0;ch<CH_;++ch) s += vp[(size_t)ch*(K_*C_)];
  float sw = 0.f;
  #pragma unroll
  for (int ch=0;ch<CH_;++ch) sw += sumawPart[((size_t)n*CH_ + ch)*K_ + k];
  float cv = f32 ? ((const float*)cen)[i] : b2f(((const bf16*)cen)[i]);
  vlad[tid] = s - cv*sw;
}

// ---------- K6: intra-norm * cluster_weights, global L2 norm, store ----------
__global__ __launch_bounds__(256) void k_final(const float* __restrict__ vlad,
                                               const void* __restrict__ clw,
                                               const void* __restrict__ x,
                                               void* __restrict__ out){
  __shared__ float s_v[K_*C_];
  __shared__ float s_ssk[K_];
  __shared__ float s_scale[K_];
  __shared__ float s_gs;
  int n = blockIdx.x, t = threadIdx.x;
  int f32 = is_f32((const unsigned short*)x);
  const float* vp = vlad + (size_t)n*K_*C_;
  for (int i=t;i<K_*C_;i+=256) s_v[i] = vp[i];
  __syncthreads();
  int k = t >> 2, q = t & 3;
  float ss = 0.f;
  for (int mm=0;mm<32;++mm){ float v = s_v[k*C_ + q + 4*mm]; ss += v*v; }
  ss += __shfl_down(ss, 2);
  ss += __shfl_down(ss, 1);
  if (q == 0) s_ssk[k] = ss;
  __syncthreads();
  if (t < K_){
    float cw = f32 ? ((const float*)clw)[t] : b2f(((const bf16*)clw)[t]);
    s_scale[t] = cw / fmaxf(sqrtf(s_ssk[t]), 1e-12f);
  }
  __syncthreads();
  if (t == 0){
    float gss = 0.f;
    for (int kk=0;kk<K_;++kk) gss += s_ssk[kk]*s_scale[kk]*s_scale[kk];
    s_gs = 1.f / fmaxf(sqrtf(gss), 1e-12f);
  }
  __syncthreads();
  float gsc = s_gs;
  if (f32){
    float* op = (float*)out + (size_t)n*K_*C_;
    for (int i=t;i<K_*C_;i+=256) op[i] = s_v[i]*s_scale[i>>7]*gsc;
  } else {
    bf16* op = (bf16*)out + (size_t)n*K_*C_;
    for (int i=t;i<K_*C_;i+=256) op[i] = __float2bfloat16(s_v[i]*s_scale[i>>7]*gsc);
  }
}

extern "C" void kernel_launch(void* const* d_in, const int* in_sizes, int n_in,
                              void* d_out, int out_size, void* d_ws, size_t ws_size,
                              hipStream_t stream){
  const void* x   = d_in[0];
  const void* cen = d_in[1];
  const void* cvw = d_in[2];
  const void* csw = d_in[3];
  const void* caw = d_in[4];
  const void* clw = d_in[5];

  char* ws = (char*)d_ws;
  bf16* WallF = (bf16*)ws;             ws += (size_t)M_*C_*2;        // 128 KB
  bf16* xnF   = (bf16*)ws;             ws += (size_t)N_*P_*C_*2;     // 18.87 MB
  bf16* xnG   = (bf16*)ws;             ws += (size_t)N_*C_*P_*2;     // 18.87 MB
  char* aBuf  = ws;                    ws += (size_t)N_*K_*P_*2;     // 9.44 MB
  unsigned short* a = (unsigned short*)aBuf;   // dead after k_vlad
  float* vlad = (float*)aBuf;                  // overlay: written by k_vred (1 MB)
  float* sal  = (float*)ws;            ws += (size_t)N_*K_*R_*4;     // 0.17 MB
  char* un = ws;
  float* salPart   = (float*)un;               // dead after k_salred
  float* vladPart  = (float*)un;               // overlay: written by k_vlad
  float* sumawPart = (float*)(un + (size_t)N_*CH_*K_*C_*4);
  ws += (size_t)N_*NB_*K_*R_*4;                                      // 12.39 MB

  k_wall  <<<dim3(M_*C_/256),       256, 0, stream>>>(cvw, csw, caw, x, WallF);
  k_norm  <<<dim3(N_*P_/128),       256, 0, stream>>>(x, xnF, xnG);
  k_gemm  <<<dim3(NB_, N_),         256, 0, stream>>>(WallF, xnF, a, salPart);
  k_salred<<<dim3((N_*K_*R_+255)/256), 256, 0, stream>>>(salPart, sal);
  k_vlad  <<<dim3(CH_, N_),         256, 0, stream>>>(xnG, a, sal, vladPart, sumawPart);
  k_vred  <<<dim3(N_*K_*C_/256),    256, 0, stream>>>(vladPart, sumawPart, cen, x, vlad);
  k_final <<<dim3(N_),              256, 0, stream>>>(vlad, clw, x, d_out);
}

// Round 3
// 163.973 us; speedup vs baseline: 1.3172x; 1.1544x over previous
//
#include <hip/hip_runtime.h>
#include <hip/hip_bf16.h>

#define N_ 32
#define C_ 128
#define H_ 48
#define W_ 48
#define P_ (H_*W_)   // 2304
#define K_ 64
#define S_ 4
#define L_ 3
#define R_ 21
#define NB_ 72       // P_/32 pixel tiles per image
#define M_ 512       // total logit rows
#define CH_ 9        // xnG chunks (256 px each)
#define CHV_ 18      // vlad split-K chunks (128 px each)

typedef __hip_bfloat16 bf16;
typedef __attribute__((ext_vector_type(8))) short   bf16x8;
typedef __attribute__((ext_vector_type(8))) unsigned short u16x8;
typedef __attribute__((ext_vector_type(4))) float   f32x4;

__device__ __forceinline__ float b2f(bf16 v){ return __bfloat162float(v); }
__device__ __forceinline__ float u2f(unsigned short u){
  union { unsigned i; float f; } v; v.i = ((unsigned)u) << 16; return v.f;
}
__device__ __forceinline__ unsigned short f2u(float f){
  bf16 h = __float2bfloat16(f);
  return *(unsigned short*)&h;
}

// wave-uniform dtype probe: 1 if x is fp32, 0 if bf16 (reads fixed 1024-elem window).
__device__ __forceinline__ int is_f32(const unsigned short* __restrict__ xb){
  int lane = threadIdx.x & 63;
  int w = 0;
  #pragma unroll
  for (int i=0;i<16;++i){
    int e = (xb[lane*16 + i] >> 7) & 0xFF;
    w += (e >= 0x8E) ? 1 : 0;
  }
  unsigned long long b = __ballot(w > 0);
  return __popcll(b) > 32;
}

// region membership for global region index r (0..20) at pixel (h,w); bf16 1.0/0.0 bits
__device__ __forceinline__ unsigned short region_bit(int r, int h, int w){
  bool m;
  if (r == 0){
    m = true;
  } else if (r < 5){
    int q = r-1, i = q>>1, j = q&1;
    m = (h>=16*i)&&(h<16*i+32)&&(w>=16*j)&&(w<16*j+32);
  } else if (r < 21){
    int q = r-5, i = q>>2, j = q&3;
    m = (h>=10*i-1)&&(h<10*i+19)&&(w>=10*j-1)&&(w<10*j+19);
  } else {
    m = false;
  }
  return m ? (unsigned short)0x3F80 : (unsigned short)0;
}

// ---------- K0: build WallF in MFMA-fragment order ----------
// frag f = (((wv*8+rt)*4+ks)*64 + lane)*8 + j  <-  row = wv*128+rt*16+(lane&15),
// c = ks*32 + ((lane>>4)&3)*8 + j. Rows: 0-63 score, 64-319 shadow, 320-511 app.
__global__ __launch_bounds__(256) void k_wall(const void* __restrict__ cvw, const void* __restrict__ csw,
                                              const void* __restrict__ caw, const void* __restrict__ x,
                                              bf16* __restrict__ WallF){
  int f32 = is_f32((const unsigned short*)x);
  int i = blockIdx.x*256 + threadIdx.x;          // 0..65535
  int j = i&7, lane = (i>>3)&63, ks = (i>>9)&3, rt = (i>>11)&7, wv = (i>>14)&3;
  int row = wv*128 + rt*16 + (lane&15);
  int c   = ks*32 + ((lane>>4)&3)*8 + j;
  int s = row*C_ + c;
  float v;
  if (s < 8192)       v = f32 ? ((const float*)cvw)[s]        : b2f(((const bf16*)cvw)[s]);
  else if (s < 40960) v = f32 ? ((const float*)csw)[s-8192]   : b2f(((const bf16*)csw)[s-8192]);
  else                v = f32 ? ((const float*)caw)[s-40960]  : b2f(((const bf16*)caw)[s-40960]);
  WallF[i] = __float2bfloat16(v);
}

// ---------- K1: L2 norm -> xnF (k_gemm B-frags) and xnG (k_vlad B-frags), both coalesced ----------
__global__ __launch_bounds__(256) void k_norm(const void* __restrict__ x,
                                              bf16* __restrict__ xnF,
                                              bf16* __restrict__ xnG){
  __shared__ float sred[2][128];
  __shared__ __align__(16) unsigned short tile[128][136];   // 34816 B, 16B-aligned rows
  int f32 = is_f32((const unsigned short*)x);
  int bi = blockIdx.x;
  int n = bi / (P_/128), tb = bi % (P_/128);
  int p0 = tb*128;
  int t = threadIdx.x, px = t&127, chh = t>>7, c0 = chh*64;

  float vals[64];
  float ss = 0.f;
  if (f32){
    const float* xb = (const float*)x + ((size_t)n*C_ + c0)*P_ + p0 + px;
    #pragma unroll
    for (int j=0;j<64;++j){ float v = xb[(size_t)j*P_]; vals[j] = v; ss += v*v; }
  } else {
    const unsigned short* xb = (const unsigned short*)x + ((size_t)n*C_ + c0)*P_ + p0 + px;
    #pragma unroll
    for (int j=0;j<64;++j){ float v = u2f(xb[(size_t)j*P_]); vals[j] = v; ss += v*v; }
  }
  sred[chh][px] = ss;
  __syncthreads();
  float invn = 1.f / fmaxf(sqrtf(sred[0][px] + sred[1][px]), 1e-12f);
  unsigned short nv[64];
  #pragma unroll
  for (int j=0;j<64;++j) nv[j] = f2u(vals[j]*invn);

  // ---- phase A: tile[c][px] ----
  #pragma unroll
  for (int j=0;j<64;++j) tile[c0+j][px] = nv[j];
  __syncthreads();
  // emit xnG (chunk ch = tb>>1 covers 256 px; this block is half hb)
  {
    int ch = tb>>1, hb = tb&1;
    size_t gbase = ((size_t)(n*CH_ + ch)*8 + hb*4)*512;
    u16x8* out = (u16x8*)xnG;
    #pragma unroll
    for (int it=0;it<8;++it){
      int o2 = t + it*256;
      int lane = o2&63, half = (o2>>6)&1, wvv = (o2>>7)&3, ksl = (o2>>9)&3;
      int c  = wvv*32 + half*16 + (lane&15);
      int pl = ksl*32 + ((lane>>4)&3)*8;
      out[gbase + o2] = *(const u16x8*)&tile[c][pl];
    }
  }
  __syncthreads();
  // ---- phase B: reuse tile as [px][c] ----
  #pragma unroll
  for (int j8=0;j8<8;++j8)
    *(u16x8*)&tile[px][c0 + j8*8] = *(const u16x8*)&nv[j8*8];
  __syncthreads();
  // emit xnF (4 gemm-tiles pb = tb*4 + pbl)
  {
    size_t fbase = (size_t)(n*NB_ + tb*4)*512;
    u16x8* out = (u16x8*)xnF;
    #pragma unroll
    for (int it=0;it<8;++it){
      int o = t + it*256;
      int lane = o&63, half = (o>>6)&1, ks = (o>>7)&3, pbl = (o>>9)&3;
      int pxr = pbl*32 + half*16 + (lane&15);
      int cc  = ks*32 + ((lane>>4)&3)*8;
      out[fbase + o] = *(const u16x8*)&tile[pxr][cc];
    }
  }
}

// ---------- K2: fused 512-row MFMA GEMM + vectorized softmax + MFMA region sums ----------
// grid (NB_=72, N_=32), 4 waves. Wave w owns rows [w*128, w*128+128).
// ldsU layout (k-major, [320][40] u16, 80B rows, conflict-free b128 at stride-20dw):
//   rows 0..63   = score row k
//   rows 64+s*64+k = shadow s of cluster k   (s-major so softmax reads are per-row vectors)
// appS overlays rows 0..191 AFTER softmax (app logits held packed in regs until then).
// Region partials: plain per-tile stores to salPart (contention-free), reduced by k_salred.
__global__ __launch_bounds__(256, 4) void k_gemm(const bf16* __restrict__ WallF,
                                                 const bf16* __restrict__ xnF,
                                                 unsigned short* __restrict__ a,
                                                 float* __restrict__ salPart){
  __shared__ __align__(16) unsigned short ldsU[320][40];    // 25600 B
  unsigned short (*appS)[40] = ldsU;                        // overlay rows 0..191
  int n = blockIdx.y, pb = blockIdx.x;
  int p0 = pb*32;
  int t = threadIdx.x, wv = t>>6, l = t&63;
  int mrow = l&15, quad = l>>4;

  const bf16* Af = WallF + ((size_t)(wv*8)*4)*512 + l*8;   // + (rt*4+ks)*512
  const bf16* Bf = xnF + (size_t)(n*NB_ + pb)*4096 + l*8;  // + (ks*2+half)*512

  f32x4 acc[8][2];
  #pragma unroll
  for (int rt=0;rt<8;++rt){ acc[rt][0] = (f32x4){0,0,0,0}; acc[rt][1] = (f32x4){0,0,0,0}; }

  #pragma unroll
  for (int ks=0;ks<4;++ks){
    bf16x8 b0 = *(const bf16x8*)(Bf + (ks*2+0)*512);
    bf16x8 b1 = *(const bf16x8*)(Bf + (ks*2+1)*512);
    #pragma unroll
    for (int rt=0;rt<8;++rt){
      bf16x8 af = *(const bf16x8*)(Af + (rt*4+ks)*512);
      acc[rt][0] = __builtin_amdgcn_mfma_f32_16x16x32_bf16(af, b0, acc[rt][0], 0,0,0);
      acc[rt][1] = __builtin_amdgcn_mfma_f32_16x16x32_bf16(af, b1, acc[rt][1], 0,0,0);
    }
  }

  // C/D: col = lane&15, row = quad*4 + reg.
  // scores/shadows -> ldsU (k-major); app rows -> packed bf16 regs (written after softmax).
  unsigned appPk[8][2][2];
  #pragma unroll
  for (int rt=0;rt<8;++rt){
    int row0 = wv*128 + rt*16;
    if (row0 < 64){
      #pragma unroll
      for (int ct=0;ct<2;++ct)
        #pragma unroll
        for (int r=0;r<4;++r)
          ldsU[row0 + quad*4 + r][ct*16 + mrow] = f2u(acc[rt][ct][r]);
    } else if (row0 < 320){
      #pragma unroll
      for (int ct=0;ct<2;++ct)
        #pragma unroll
        for (int r=0;r<4;++r){
          int sr = row0 + quad*4 + r - 64;                  // = k*4 + s
          ldsU[64 + (sr&3)*64 + (sr>>2)][ct*16 + mrow] = f2u(acc[rt][ct][r]);
        }
    } else {
      #pragma unroll
      for (int ct=0;ct<2;++ct){
        appPk[rt][ct][0] = (unsigned)f2u(fmaxf(acc[rt][ct][0],0.f))
                         | ((unsigned)f2u(fmaxf(acc[rt][ct][1],0.f)) << 16);
        appPk[rt][ct][1] = (unsigned)f2u(fmaxf(acc[rt][ct][2],0.f))
                         | ((unsigned)f2u(fmaxf(acc[rt][ct][3],0.f)) << 16);
      }
    }
  }
  __syncthreads();

  // ---- softmax: lane = k, wave wv = pixel-group (8 px). 5 x ds_read_b128, no conflicts.
  // |logit| <= ~1.2 (normalized x, 0.1-scaled weights) -> max-subtraction safely dropped.
  {
    int pg = wv;
    u16x8 s8  = *(const u16x8*)&ldsU[l      ][pg*8];
    u16x8 h0v = *(const u16x8*)&ldsU[64  + l][pg*8];
    u16x8 h1v = *(const u16x8*)&ldsU[128 + l][pg*8];
    u16x8 h2v = *(const u16x8*)&ldsU[192 + l][pg*8];
    u16x8 h3v = *(const u16x8*)&ldsU[256 + l][pg*8];
    float ez[8], Zr[8];
    #pragma unroll
    for (int j=0;j<8;++j){ ez[j] = __expf(u2f((unsigned short)s8[j])); Zr[j] = ez[j]; }
    #pragma unroll
    for (int st=1; st<64; st<<=1){
      #pragma unroll
      for (int j=0;j<8;++j) Zr[j] += __shfl_xor(Zr[j], st);
    }
    size_t tile = (size_t)n*NB_ + pb;
    #pragma unroll
    for (int j=0;j<8;++j){
      float e0 = ez[j];
      float den = e0 + __expf(u2f((unsigned short)h0v[j]))
                     + __expf(u2f((unsigned short)h1v[j]))
                     + __expf(u2f((unsigned short)h2v[j]))
                     + __expf(u2f((unsigned short)h3v[j]));
      // a = (e0/Z) * (e0/den); coalesced 128B row store
      a[tile*2048 + (size_t)(pg*8+j)*64 + l] = f2u(__fdividef(e0*e0, Zr[j]*den));
    }
  }
  __syncthreads();   // all ldsU reads done; safe to overlay appS

  // ---- app rows (relu'd bf16, from regs) -> appS ----
  #pragma unroll
  for (int rt=0;rt<8;++rt){
    int row0 = wv*128 + rt*16;
    if (row0 >= 320){
      int ar0 = row0 - 320 + quad*4;
      #pragma unroll
      for (int ct=0;ct<2;++ct){
        appS[ar0+0][ct*16+mrow] = (unsigned short)(appPk[rt][ct][0] & 0xffff);
        appS[ar0+1][ct*16+mrow] = (unsigned short)(appPk[rt][ct][0] >> 16);
        appS[ar0+2][ct*16+mrow] = (unsigned short)(appPk[rt][ct][1] & 0xffff);
        appS[ar0+3][ct*16+mrow] = (unsigned short)(appPk[rt][ct][1] >> 16);
      }
    }
  }
  __syncthreads();

  // ---- region sums via MFMA: salPart[tile][k][r] = sum_p app[k][p] * M[r][p] ----
  // B-frag: col = lane&15 = region r (tile0: r, tile1: 16+r), k-dim px = quad*8+j.
  bf16x8 bm0, bm1;
  #pragma unroll
  for (int j=0;j<8;++j){
    int p = p0 + quad*8 + j;
    int h = p/48, wc = p - h*48;
    bm0[j] = (short)region_bit(mrow,      h, wc);
    bm1[j] = (short)region_bit(16 + mrow, h, wc);
  }
  f32x4 racc[3][2];
  #pragma unroll
  for (int i=0;i<3;++i){ racc[i][0] = (f32x4){0,0,0,0}; racc[i][1] = (f32x4){0,0,0,0}; }
  #pragma unroll
  for (int i=0;i<3;++i){
    int rt = wv*3 + i;                                     // 12 row-tiles over 4 waves
    bf16x8 af = *(const bf16x8*)&appS[rt*16 + mrow][quad*8];
    racc[i][0] = __builtin_amdgcn_mfma_f32_16x16x32_bf16(af, bm0, racc[i][0], 0,0,0);
    racc[i][1] = __builtin_amdgcn_mfma_f32_16x16x32_bf16(af, bm1, racc[i][1], 0,0,0);
  }
  // D: col = lane&15 = r, row = quad*4+reg = app row. Each (k,r) written exactly once.
  {
    size_t tile = (size_t)n*NB_ + pb;
    float* sp = salPart + tile*(K_*R_);
    #pragma unroll
    for (int i=0;i<3;++i){
      int rt = wv*3 + i;
      int kb = rt*16 + quad*4;
      if (rt < 4){                       // level0 rows 0..63: region col 0 only
        if (mrow == 0){
          #pragma unroll
          for (int r=0;r<4;++r) sp[(size_t)(kb+r)*R_] = racc[i][0][r];
        }
      } else if (rt < 8){                // level1 rows 64..127: cols 1..4
        if (mrow >= 1 && mrow <= 4){
          #pragma unroll
          for (int r=0;r<4;++r) sp[(size_t)(kb+r-64)*R_ + mrow] = racc[i][0][r];
        }
      } else {                           // level2 rows 128..191: cols 5..20
        if (mrow >= 5){
          #pragma unroll
          for (int r=0;r<4;++r) sp[(size_t)(kb+r-128)*R_ + mrow] = racc[i][0][r];
        } else {
          #pragma unroll
          for (int r=0;r<4;++r) sp[(size_t)(kb+r-128)*R_ + 16 + mrow] = racc[i][1][r];
        }
      }
    }
  }
}

// ---------- K3: reduce 72 tile partials -> sal[n][k][21] ----------
__global__ __launch_bounds__(256) void k_salred(const float* __restrict__ salPart,
                                                float* __restrict__ sal){
  int tid = blockIdx.x*256 + threadIdx.x;
  if (tid >= N_*K_*R_) return;
  int n = tid / (K_*R_), i = tid - n*(K_*R_);
  const float* sp = salPart + (size_t)n*NB_*(K_*R_) + i;
  float s = 0.f;
  #pragma unroll 8
  for (int b=0;b<NB_;++b) s += sp[(size_t)b*(K_*R_)];
  sal[tid] = s;
}

// ---------- K4: vlad partials via MFMA. Block = (128-px chunk, n), 512 thr / 8 waves. ----------
// Split-K over CHV_=18 chunks for TLP (was 9x256px @ 4 waves -> 8.9% occupancy, latency-bound).
__global__ __launch_bounds__(512) void k_vlad(const bf16* __restrict__ xnG,
                                              const unsigned short* __restrict__ a,
                                              const float* __restrict__ sal,
                                              float* __restrict__ vladPart,
                                              float* __restrict__ sumawPart){
  __shared__ float s_sal[K_][R_];                          // 5376 B
  __shared__ __align__(16) unsigned short awL[4][K_][40];  // 20480 B
  __shared__ float s_part[4][K_];                          // 1024 B
  int c2 = blockIdx.x, n = blockIdx.y, t = threadIdx.x;
  int p0 = c2*128;
  for (int i=t;i<K_*R_;i+=512) ((float*)s_sal)[i] = sal[(size_t)n*K_*R_ + i];
  __syncthreads();

  // ---- aw = a * (M^T sal) for this chunk: thread = (pixel pxl, 16-k group kq) ----
  {
    int pxl = t & 127, kq = t>>7;
    int pbl = pxl>>5, px = pxl&31;
    int p = p0 + pxl;
    int h = p/48, wc = p - h*48;
    bool h1[2], w1[2], h2[4], w2[4];
    #pragma unroll
    for (int i=0;i<2;++i){ h1[i] = (h>=16*i)&&(h<16*i+32); w1[i] = (wc>=16*i)&&(wc<16*i+32); }
    #pragma unroll
    for (int i=0;i<4;++i){ h2[i] = (h>=10*i-1)&&(h<10*i+19); w2[i] = (wc>=10*i-1)&&(wc<10*i+19); }
    const unsigned short* at = a + ((size_t)((n*NB_ + c2*4 + pbl)*32 + px))*K_ + kq*16;
    u16x8 av[2];
    av[0] = *(const u16x8*)at;
    av[1] = *(const u16x8*)(at + 8);
    #pragma unroll
    for (int kk=0;kk<16;++kk){
      int k = kq*16 + kk;
      float w = s_sal[k][0];
      #pragma unroll
      for (int i=0;i<2;++i) if (h1[i])
        #pragma unroll
        for (int j=0;j<2;++j) if (w1[j]) w += s_sal[k][1+2*i+j];
      #pragma unroll
      for (int i=0;i<4;++i) if (h2[i])
        #pragma unroll
        for (int j=0;j<4;++j) if (w2[j]) w += s_sal[k][5+4*i+j];
      awL[pbl][k][px] = f2u(u2f(av[kk>>3][kk&7]) * w);
    }
  }
  __syncthreads();
  // ---- row sums for sum_p(aw) ----
  if (t < 256){
    int k = t&63, qr = t>>6;
    float s = 0.f;
    #pragma unroll 8
    for (int j=0;j<32;++j) s += u2f(awL[qr][k][j]);
    s_part[qr][k] = s;
  }
  __syncthreads();

  // ---- MFMA: wave = (c-quadrant wvc, k-half mh). 16 MFMA/wave. ----
  int wave = t>>6, l = t&63, mrow = l&15, quad = l>>4;
  int wvc = wave&3, mh = wave>>2;
  f32x4 acc[2][2];
  #pragma unroll
  for (int mtl=0;mtl<2;++mtl){ acc[mtl][0] = (f32x4){0,0,0,0}; acc[mtl][1] = (f32x4){0,0,0,0}; }
  const bf16* Gf = xnG + (size_t)(n*CH_ + (c2>>1))*32768 + l*8;  // + ((ks*4+wvc)*2+half)*512
  int ksbase = (c2&1)*4;
  #pragma unroll
  for (int ksl=0;ksl<4;++ksl){
    int ks = ksbase + ksl;
    bf16x8 b0 = *(const bf16x8*)(Gf + ((ks*4+wvc)*2+0)*512);
    bf16x8 b1 = *(const bf16x8*)(Gf + ((ks*4+wvc)*2+1)*512);
    #pragma unroll
    for (int mtl=0;mtl<2;++mtl){
      bf16x8 af = *(const bf16x8*)((const bf16*)&awL[ksl][(mh*2+mtl)*16 + mrow][quad*8]);
      acc[mtl][0] = __builtin_amdgcn_mfma_f32_16x16x32_bf16(af, b0, acc[mtl][0], 0,0,0);
      acc[mtl][1] = __builtin_amdgcn_mfma_f32_16x16x32_bf16(af, b1, acc[mtl][1], 0,0,0);
    }
  }
  float* vp = vladPart + ((size_t)(n*CHV_ + c2))*(K_*C_);
  #pragma unroll
  for (int mtl=0;mtl<2;++mtl){
    #pragma unroll
    for (int ct=0;ct<2;++ct){
      int c = wvc*32 + ct*16 + mrow;
      #pragma unroll
      for (int r=0;r<4;++r){
        int k = (mh*2+mtl)*16 + quad*4 + r;
        vp[k*C_ + c] = acc[mtl][ct][r];
      }
    }
  }
  if (t < K_){
    float s = s_part[0][t] + s_part[1][t] + s_part[2][t] + s_part[3][t];
    sumawPart[((size_t)n*CHV_ + c2)*K_ + t] = s;
  }
}

// ---------- K5: parallel chunk reduce + centroid term -> vlad ----------
__global__ __launch_bounds__(256) void k_vred(const float* __restrict__ vladPart,
                                              const float* __restrict__ sumawPart,
                                              const void* __restrict__ cen,
                                              const void* __restrict__ x,
                                              float* __restrict__ vlad){
  int f32 = is_f32((const unsigned short*)x);
  int tid = blockIdx.x*256 + threadIdx.x;       // < N_*K_*C_ = 262144
  int n = tid >> 13;
  int i = tid & 8191;
  int k = i >> 7;
  const float* vp = vladPart + (size_t)n*CHV_*(K_*C_) + i;
  float s = 0.f;
  #pragma unroll
  for (int ch=0;ch<CHV_;++ch) s += vp[(size_t)ch*(K_*C_)];
  float sw = 0.f;
  #pragma unroll
  for (int ch=0;ch<CHV_;++ch) sw += sumawPart[((size_t)n*CHV_ + ch)*K_ + k];
  float cv = f32 ? ((const float*)cen)[i] : b2f(((const bf16*)cen)[i]);
  vlad[tid] = s - cv*sw;
}

// ---------- K6: intra-norm * cluster_weights, global L2 norm, store ----------
__global__ __launch_bounds__(256) void k_final(const float* __restrict__ vlad,
                                               const void* __restrict__ clw,
                                               const void* __restrict__ x,
                                               void* __restrict__ out){
  __shared__ float s_v[K_*C_];
  __shared__ float s_ssk[K_];
  __shared__ float s_scale[K_];
  __shared__ float s_gs;
  int n = blockIdx.x, t = threadIdx.x;
  int f32 = is_f32((const unsigned short*)x);
  const float* vp = vlad + (size_t)n*K_*C_;
  for (int i=t;i<K_*C_;i+=256) s_v[i] = vp[i];
  __syncthreads();
  int k = t >> 2, q = t & 3;
  float ss = 0.f;
  for (int mm=0;mm<32;++mm){ float v = s_v[k*C_ + q + 4*mm]; ss += v*v; }
  ss += __shfl_down(ss, 2);
  ss += __shfl_down(ss, 1);
  if (q == 0) s_ssk[k] = ss;
  __syncthreads();
  if (t < K_){
    float cw = f32 ? ((const float*)clw)[t] : b2f(((const bf16*)clw)[t]);
    s_scale[t] = cw / fmaxf(sqrtf(s_ssk[t]), 1e-12f);
  }
  __syncthreads();
  if (t == 0){
    float gss = 0.f;
    for (int kk=0;kk<K_;++kk) gss += s_ssk[kk]*s_scale[kk]*s_scale[kk];
    s_gs = 1.f / fmaxf(sqrtf(gss), 1e-12f);
  }
  __syncthreads();
  float gsc = s_gs;
  if (f32){
    float* op = (float*)out + (size_t)n*K_*C_;
    for (int i=t;i<K_*C_;i+=256) op[i] = s_v[i]*s_scale[i>>7]*gsc;
  } else {
    bf16* op = (bf16*)out + (size_t)n*K_*C_;
    for (int i=t;i<K_*C_;i+=256) op[i] = __float2bfloat16(s_v[i]*s_scale[i>>7]*gsc);
  }
}

extern "C" void kernel_launch(void* const* d_in, const int* in_sizes, int n_in,
                              void* d_out, int out_size, void* d_ws, size_t ws_size,
                              hipStream_t stream){
  const void* x   = d_in[0];
  const void* cen = d_in[1];
  const void* cvw = d_in[2];
  const void* csw = d_in[3];
  const void* caw = d_in[4];
  const void* clw = d_in[5];

  char* ws = (char*)d_ws;
  bf16* WallF = (bf16*)ws;             ws += (size_t)M_*C_*2;        // 128 KB
  bf16* xnF   = (bf16*)ws;             ws += (size_t)N_*P_*C_*2;     // 18.87 MB
  bf16* xnG   = (bf16*)ws;             ws += (size_t)N_*C_*P_*2;     // 18.87 MB
  char* aBuf  = ws;                    ws += (size_t)N_*K_*P_*2;     // 9.44 MB
  unsigned short* a = (unsigned short*)aBuf;   // dead after k_vlad
  float* vlad = (float*)aBuf;                  // overlay: written by k_vred (1 MB)
  float* sal  = (float*)ws;            ws += (size_t)N_*K_*R_*4;     // 0.17 MB
  char* un = ws;
  float* salPart   = (float*)un;               // dead after k_salred
  float* sumawPart = (float*)un;               // overlay: written by k_vlad (147 KB)
  ws += (size_t)N_*NB_*K_*R_*4;                                      // 12.39 MB
  // vladPart overlays xnF (dead after k_gemm); N_*CHV_*K_*C_*4 == N_*P_*C_*2 exactly.
  float* vladPart = (float*)xnF;

  k_wall  <<<dim3(M_*C_/256),       256, 0, stream>>>(cvw, csw, caw, x, WallF);
  k_norm  <<<dim3(N_*P_/128),       256, 0, stream>>>(x, xnF, xnG);
  k_gemm  <<<dim3(NB_, N_),         256, 0, stream>>>(WallF, xnF, a, salPart);
  k_salred<<<dim3((N_*K_*R_+255)/256), 256, 0, stream>>>(salPart, sal);
  k_vlad  <<<dim3(CHV_, N_),        512, 0, stream>>>(xnG, a, sal, vladPart, sumawPart);
  k_vred  <<<dim3(N_*K_*C_/256),    256, 0, stream>>>(vladPart, sumawPart, cen, x, vlad);
  k_final <<<dim3(N_),              256, 0, stream>>>(vlad, clw, x, d_out);
}

// Round 4
// 153.478 us; speedup vs baseline: 1.4072x; 1.0684x over previous
//
#include <hip/hip_runtime.h>
#include <hip/hip_bf16.h>

#define N_ 32
#define C_ 128
#define H_ 48
#define W_ 48
#define P_ (H_*W_)   // 2304
#define K_ 64
#define S_ 4
#define L_ 3
#define R_ 21
#define NB_ 72       // P_/32 pixel tiles per image
#define M_ 512       // total logit rows
#define CH_ 9        // xnG chunks (256 px each)
#define CHV_ 18      // vlad split-K chunks (128 px each)

typedef __hip_bfloat16 bf16;
typedef __attribute__((ext_vector_type(8))) short   bf16x8;
typedef __attribute__((ext_vector_type(8))) unsigned short u16x8;
typedef __attribute__((ext_vector_type(4))) unsigned short u16x4;
typedef __attribute__((ext_vector_type(4))) float   f32x4;

__device__ __forceinline__ float b2f(bf16 v){ return __bfloat162float(v); }
__device__ __forceinline__ float u2f(unsigned short u){
  union { unsigned i; float f; } v; v.i = ((unsigned)u) << 16; return v.f;
}
__device__ __forceinline__ unsigned short f2u(float f){
  bf16 h = __float2bfloat16(f);
  return *(unsigned short*)&h;
}

// wave-uniform dtype probe: 1 if x is fp32, 0 if bf16 (reads fixed 1024-elem window).
__device__ __forceinline__ int is_f32(const unsigned short* __restrict__ xb){
  int lane = threadIdx.x & 63;
  int w = 0;
  #pragma unroll
  for (int i=0;i<16;++i){
    int e = (xb[lane*16 + i] >> 7) & 0xFF;
    w += (e >= 0x8E) ? 1 : 0;
  }
  unsigned long long b = __ballot(w > 0);
  return __popcll(b) > 32;
}

// region membership for global region index r (0..20) at pixel (h,w); bf16 1.0/0.0 bits
__device__ __forceinline__ unsigned short region_bit(int r, int h, int w){
  bool m;
  if (r == 0){
    m = true;
  } else if (r < 5){
    int q = r-1, i = q>>1, j = q&1;
    m = (h>=16*i)&&(h<16*i+32)&&(w>=16*j)&&(w<16*j+32);
  } else if (r < 21){
    int q = r-5, i = q>>2, j = q&3;
    m = (h>=10*i-1)&&(h<10*i+19)&&(w>=10*j-1)&&(w<10*j+19);
  } else {
    m = false;
  }
  return m ? (unsigned short)0x3F80 : (unsigned short)0;
}

// ---------- K0: build WallF in MFMA-fragment order ----------
// frag f = ((rt_g*4+ks)*64 + lane)*8 + j  <-  row = rt_g*16+(lane&15),
// c = ks*32 + ((lane>>4)&3)*8 + j. Rows: 0-63 score, 64-319 shadow, 320-511 app.
__global__ __launch_bounds__(256) void k_wall(const void* __restrict__ cvw, const void* __restrict__ csw,
                                              const void* __restrict__ caw, const void* __restrict__ x,
                                              bf16* __restrict__ WallF){
  int f32 = is_f32((const unsigned short*)x);
  int i = blockIdx.x*256 + threadIdx.x;          // 0..65535
  int j = i&7, lane = (i>>3)&63, ks = (i>>9)&3, rt = (i>>11)&31;
  int row = rt*16 + (lane&15);
  int c   = ks*32 + ((lane>>4)&3)*8 + j;
  int s = row*C_ + c;
  float v;
  if (s < 8192)       v = f32 ? ((const float*)cvw)[s]        : b2f(((const bf16*)cvw)[s]);
  else if (s < 40960) v = f32 ? ((const float*)csw)[s-8192]   : b2f(((const bf16*)csw)[s-8192]);
  else                v = f32 ? ((const float*)caw)[s-40960]  : b2f(((const bf16*)caw)[s-40960]);
  WallF[i] = __float2bfloat16(v);
}

// ---------- K1: L2 norm -> xnF (k_gemm B-frags) and xnG (k_vlad B-frags), both coalesced ----------
__global__ __launch_bounds__(256) void k_norm(const void* __restrict__ x,
                                              bf16* __restrict__ xnF,
                                              bf16* __restrict__ xnG){
  __shared__ float sred[2][128];
  __shared__ __align__(16) unsigned short tile[128][136];   // 34816 B, 16B-aligned rows
  int f32 = is_f32((const unsigned short*)x);
  int bi = blockIdx.x;
  int n = bi / (P_/128), tb = bi % (P_/128);
  int p0 = tb*128;
  int t = threadIdx.x, px = t&127, chh = t>>7, c0 = chh*64;

  float vals[64];
  float ss = 0.f;
  if (f32){
    const float* xb = (const float*)x + ((size_t)n*C_ + c0)*P_ + p0 + px;
    #pragma unroll
    for (int j=0;j<64;++j){ float v = xb[(size_t)j*P_]; vals[j] = v; ss += v*v; }
  } else {
    const unsigned short* xb = (const unsigned short*)x + ((size_t)n*C_ + c0)*P_ + p0 + px;
    #pragma unroll
    for (int j=0;j<64;++j){ float v = u2f(xb[(size_t)j*P_]); vals[j] = v; ss += v*v; }
  }
  sred[chh][px] = ss;
  __syncthreads();
  float invn = 1.f / fmaxf(sqrtf(sred[0][px] + sred[1][px]), 1e-12f);
  unsigned short nv[64];
  #pragma unroll
  for (int j=0;j<64;++j) nv[j] = f2u(vals[j]*invn);

  // ---- phase A: tile[c][px] ----
  #pragma unroll
  for (int j=0;j<64;++j) tile[c0+j][px] = nv[j];
  __syncthreads();
  // emit xnG (chunk ch = tb>>1 covers 256 px; this block is half hb)
  {
    int ch = tb>>1, hb = tb&1;
    size_t gbase = ((size_t)(n*CH_ + ch)*8 + hb*4)*512;
    u16x8* out = (u16x8*)xnG;
    #pragma unroll
    for (int it=0;it<8;++it){
      int o2 = t + it*256;
      int lane = o2&63, half = (o2>>6)&1, wvv = (o2>>7)&3, ksl = (o2>>9)&3;
      int c  = wvv*32 + half*16 + (lane&15);
      int pl = ksl*32 + ((lane>>4)&3)*8;
      out[gbase + o2] = *(const u16x8*)&tile[c][pl];
    }
  }
  __syncthreads();
  // ---- phase B: reuse tile as [px][c] ----
  #pragma unroll
  for (int j8=0;j8<8;++j8)
    *(u16x8*)&tile[px][c0 + j8*8] = *(const u16x8*)&nv[j8*8];
  __syncthreads();
  // emit xnF (4 gemm-tiles pb = tb*4 + pbl)
  {
    size_t fbase = (size_t)(n*NB_ + tb*4)*512;
    u16x8* out = (u16x8*)xnF;
    #pragma unroll
    for (int it=0;it<8;++it){
      int o = t + it*256;
      int lane = o&63, half = (o>>6)&1, ks = (o>>7)&3, pbl = (o>>9)&3;
      int pxr = pbl*32 + half*16 + (lane&15);
      int cc  = ks*32 + ((lane>>4)&3)*8;
      out[fbase + o] = *(const u16x8*)&tile[pxr][cc];
    }
  }
}

// ---------- K2: fused 512-row MFMA GEMM + softmax + MFMA region sums ----------
// grid (NB_=72, N_=32), 512 thr / 8 waves; wave w owns rows [w*64, w*64+64) (4 row-tiles).
// Single barrier: phase 1 writes ldsU (scores k-major, shadows s-major) AND appS (relu'd);
// phase 2 (softmax + region MFMA) is read-only. appS is a separate array (no overlay).
__global__ __launch_bounds__(512, 4) void k_gemm(const bf16* __restrict__ WallF,
                                                 const bf16* __restrict__ xnF,
                                                 unsigned short* __restrict__ a,
                                                 float* __restrict__ salPart){
  __shared__ __align__(16) unsigned short ldsU[320][40];    // 25600 B
  __shared__ __align__(16) unsigned short appS[192][40];    // 15360 B
  int n = blockIdx.y, pb = blockIdx.x;
  int p0 = pb*32;
  int t = threadIdx.x, w = t>>6, l = t&63;
  int mrow = l&15, quad = l>>4;

  const bf16* Af = WallF + ((size_t)(w*4)*4)*512 + l*8;    // + (rtl*4+ks)*512
  const bf16* Bf = xnF + (size_t)(n*NB_ + pb)*4096 + l*8;  // + (ks*2+half)*512

  f32x4 acc[4][2];
  #pragma unroll
  for (int rtl=0;rtl<4;++rtl){ acc[rtl][0] = (f32x4){0,0,0,0}; acc[rtl][1] = (f32x4){0,0,0,0}; }

  #pragma unroll
  for (int ks=0;ks<4;++ks){
    bf16x8 b0 = *(const bf16x8*)(Bf + (ks*2+0)*512);
    bf16x8 b1 = *(const bf16x8*)(Bf + (ks*2+1)*512);
    #pragma unroll
    for (int rtl=0;rtl<4;++rtl){
      bf16x8 af = *(const bf16x8*)(Af + (rtl*4+ks)*512);
      acc[rtl][0] = __builtin_amdgcn_mfma_f32_16x16x32_bf16(af, b0, acc[rtl][0], 0,0,0);
      acc[rtl][1] = __builtin_amdgcn_mfma_f32_16x16x32_bf16(af, b1, acc[rtl][1], 0,0,0);
    }
  }

  // C/D: col = lane&15, row = quad*4 + reg. Wave-uniform routing by row range.
  #pragma unroll
  for (int rtl=0;rtl<4;++rtl){
    int row0 = w*64 + rtl*16;
    if (row0 < 64){                       // scores, k-major
      #pragma unroll
      for (int ct=0;ct<2;++ct)
        #pragma unroll
        for (int r=0;r<4;++r)
          ldsU[row0 + quad*4 + r][ct*16 + mrow] = f2u(acc[rtl][ct][r]);
    } else if (row0 < 320){               // shadows, s-major: row 64 + s*64 + k
      #pragma unroll
      for (int ct=0;ct<2;++ct)
        #pragma unroll
        for (int r=0;r<4;++r){
          int sr = row0 + quad*4 + r - 64;                  // = k*4 + s
          ldsU[64 + (sr&3)*64 + (sr>>2)][ct*16 + mrow] = f2u(acc[rtl][ct][r]);
        }
    } else {                              // app rows, relu'd, direct to appS
      int ar0 = row0 - 320 + quad*4;
      #pragma unroll
      for (int ct=0;ct<2;++ct)
        #pragma unroll
        for (int r=0;r<4;++r)
          appS[ar0 + r][ct*16 + mrow] = f2u(fmaxf(acc[rtl][ct][r], 0.f));
    }
  }
  __syncthreads();   // the only barrier

  // ---- softmax: lane = k, wave w = pixel-group (4 px). 5 x ds_read_b64, read-only.
  // |logit| <= ~1.2 (normalized x, 0.1-scaled weights) -> max-subtraction safely dropped.
  {
    u16x4 s4  = *(const u16x4*)&ldsU[l      ][w*4];
    u16x4 h0v = *(const u16x4*)&ldsU[64  + l][w*4];
    u16x4 h1v = *(const u16x4*)&ldsU[128 + l][w*4];
    u16x4 h2v = *(const u16x4*)&ldsU[192 + l][w*4];
    u16x4 h3v = *(const u16x4*)&ldsU[256 + l][w*4];
    float ez[4], Zr[4];
    #pragma unroll
    for (int j=0;j<4;++j){ ez[j] = __expf(u2f((unsigned short)s4[j])); Zr[j] = ez[j]; }
    #pragma unroll
    for (int st=1; st<64; st<<=1){
      #pragma unroll
      for (int j=0;j<4;++j) Zr[j] += __shfl_xor(Zr[j], st);
    }
    size_t tile = (size_t)n*NB_ + pb;
    #pragma unroll
    for (int j=0;j<4;++j){
      float e0 = ez[j];
      float den = e0 + __expf(u2f((unsigned short)h0v[j]))
                     + __expf(u2f((unsigned short)h1v[j]))
                     + __expf(u2f((unsigned short)h2v[j]))
                     + __expf(u2f((unsigned short)h3v[j]));
      // a = (e0/Z) * (e0/den); coalesced 128B row store
      a[tile*2048 + (size_t)(w*4+j)*64 + l] = f2u(__fdividef(e0*e0, Zr[j]*den));
    }
  }

  // ---- region sums via MFMA: salPart[tile][k][r] = sum_p app[k][p] * M[r][p] ----
  // B-frag: col = lane&15 = region r (tile0: r, tile1: 16+r), K-dim px = quad*8+j.
  // 12 app row-tiles over 8 waves: w<4 -> {2w, 2w+1} (levels 0/1, bm0 only);
  //                                w>=4 -> {8+(w-4)} (level 2, bm0+bm1).
  bf16x8 bm0;
  #pragma unroll
  for (int j=0;j<8;++j){
    int p = p0 + quad*8 + j;
    int h = p/48, wc = p - h*48;
    bm0[j] = (short)region_bit(mrow, h, wc);
  }
  size_t tile = (size_t)n*NB_ + pb;
  float* sp = salPart + tile*(K_*R_);
  if (w < 4){
    #pragma unroll
    for (int i=0;i<2;++i){
      int rt = w*2 + i;
      bf16x8 af = *(const bf16x8*)&appS[rt*16 + mrow][quad*8];
      f32x4 r0 = (f32x4){0,0,0,0};
      r0 = __builtin_amdgcn_mfma_f32_16x16x32_bf16(af, bm0, r0, 0,0,0);
      int kb = rt*16 + quad*4;
      if (rt < 4){                       // level0: region col 0 only
        if (mrow == 0){
          #pragma unroll
          for (int r=0;r<4;++r) sp[(size_t)(kb+r)*R_] = r0[r];
        }
      } else {                           // level1: cols 1..4
        if (mrow >= 1 && mrow <= 4){
          #pragma unroll
          for (int r=0;r<4;++r) sp[(size_t)(kb+r-64)*R_ + mrow] = r0[r];
        }
      }
    }
  } else {
    int rt = 8 + (w-4);                  // level2: cols 5..20
    bf16x8 bm1;
    #pragma unroll
    for (int j=0;j<8;++j){
      int p = p0 + quad*8 + j;
      int h = p/48, wc = p - h*48;
      bm1[j] = (short)region_bit(16 + mrow, h, wc);
    }
    bf16x8 af = *(const bf16x8*)&appS[rt*16 + mrow][quad*8];
    f32x4 r0 = (f32x4){0,0,0,0}, r1 = (f32x4){0,0,0,0};
    r0 = __builtin_amdgcn_mfma_f32_16x16x32_bf16(af, bm0, r0, 0,0,0);
    r1 = __builtin_amdgcn_mfma_f32_16x16x32_bf16(af, bm1, r1, 0,0,0);
    int kb = rt*16 + quad*4;
    if (mrow >= 5){
      #pragma unroll
      for (int r=0;r<4;++r) sp[(size_t)(kb+r-128)*R_ + mrow] = r0[r];
    } else {
      #pragma unroll
      for (int r=0;r<4;++r) sp[(size_t)(kb+r-128)*R_ + 16 + mrow] = r1[r];
    }
  }
}

// ---------- K3: reduce 72 tile partials -> sal[n][k][21] ----------
__global__ __launch_bounds__(256) void k_salred(const float* __restrict__ salPart,
                                                float* __restrict__ sal){
  int tid = blockIdx.x*256 + threadIdx.x;
  if (tid >= N_*K_*R_) return;
  int n = tid / (K_*R_), i = tid - n*(K_*R_);
  const float* sp = salPart + (size_t)n*NB_*(K_*R_) + i;
  float s = 0.f;
  #pragma unroll 8
  for (int b=0;b<NB_;++b) s += sp[(size_t)b*(K_*R_)];
  sal[tid] = s;
}

// ---------- K4: vlad partials via MFMA. Block = (128-px chunk, n), 512 thr / 8 waves. ----------
// Split-K over CHV_=18 chunks for TLP (was 9x256px @ 4 waves -> 8.9% occupancy, latency-bound).
__global__ __launch_bounds__(512) void k_vlad(const bf16* __restrict__ xnG,
                                              const unsigned short* __restrict__ a,
                                              const float* __restrict__ sal,
                                              float* __restrict__ vladPart,
                                              float* __restrict__ sumawPart){
  __shared__ float s_sal[K_][R_];                          // 5376 B
  __shared__ __align__(16) unsigned short awL[4][K_][40];  // 20480 B
  __shared__ float s_part[4][K_];                          // 1024 B
  int c2 = blockIdx.x, n = blockIdx.y, t = threadIdx.x;
  int p0 = c2*128;
  for (int i=t;i<K_*R_;i+=512) ((float*)s_sal)[i] = sal[(size_t)n*K_*R_ + i];
  __syncthreads();

  // ---- aw = a * (M^T sal) for this chunk: thread = (pixel pxl, 16-k group kq) ----
  {
    int pxl = t & 127, kq = t>>7;
    int pbl = pxl>>5, px = pxl&31;
    int p = p0 + pxl;
    int h = p/48, wc = p - h*48;
    bool h1[2], w1[2], h2[4], w2[4];
    #pragma unroll
    for (int i=0;i<2;++i){ h1[i] = (h>=16*i)&&(h<16*i+32); w1[i] = (wc>=16*i)&&(wc<16*i+32); }
    #pragma unroll
    for (int i=0;i<4;++i){ h2[i] = (h>=10*i-1)&&(h<10*i+19); w2[i] = (wc>=10*i-1)&&(wc<10*i+19); }
    const unsigned short* at = a + ((size_t)((n*NB_ + c2*4 + pbl)*32 + px))*K_ + kq*16;
    u16x8 av[2];
    av[0] = *(const u16x8*)at;
    av[1] = *(const u16x8*)(at + 8);
    #pragma unroll
    for (int kk=0;kk<16;++kk){
      int k = kq*16 + kk;
      float w = s_sal[k][0];
      #pragma unroll
      for (int i=0;i<2;++i) if (h1[i])
        #pragma unroll
        for (int j=0;j<2;++j) if (w1[j]) w += s_sal[k][1+2*i+j];
      #pragma unroll
      for (int i=0;i<4;++i) if (h2[i])
        #pragma unroll
        for (int j=0;j<4;++j) if (w2[j]) w += s_sal[k][5+4*i+j];
      awL[pbl][k][px] = f2u(u2f(av[kk>>3][kk&7]) * w);
    }
  }
  __syncthreads();
  // ---- row sums for sum_p(aw) ----
  if (t < 256){
    int k = t&63, qr = t>>6;
    float s = 0.f;
    #pragma unroll 8
    for (int j=0;j<32;++j) s += u2f(awL[qr][k][j]);
    s_part[qr][k] = s;
  }
  __syncthreads();

  // ---- MFMA: wave = (c-quadrant wvc, k-half mh). 16 MFMA/wave. ----
  int wave = t>>6, l = t&63, mrow = l&15, quad = l>>4;
  int wvc = wave&3, mh = wave>>2;
  f32x4 acc[2][2];
  #pragma unroll
  for (int mtl=0;mtl<2;++mtl){ acc[mtl][0] = (f32x4){0,0,0,0}; acc[mtl][1] = (f32x4){0,0,0,0}; }
  const bf16* Gf = xnG + (size_t)(n*CH_ + (c2>>1))*32768 + l*8;  // + ((ks*4+wvc)*2+half)*512
  int ksbase = (c2&1)*4;
  #pragma unroll
  for (int ksl=0;ksl<4;++ksl){
    int ks = ksbase + ksl;
    bf16x8 b0 = *(const bf16x8*)(Gf + ((ks*4+wvc)*2+0)*512);
    bf16x8 b1 = *(const bf16x8*)(Gf + ((ks*4+wvc)*2+1)*512);
    #pragma unroll
    for (int mtl=0;mtl<2;++mtl){
      bf16x8 af = *(const bf16x8*)((const bf16*)&awL[ksl][(mh*2+mtl)*16 + mrow][quad*8]);
      acc[mtl][0] = __builtin_amdgcn_mfma_f32_16x16x32_bf16(af, b0, acc[mtl][0], 0,0,0);
      acc[mtl][1] = __builtin_amdgcn_mfma_f32_16x16x32_bf16(af, b1, acc[mtl][1], 0,0,0);
    }
  }
  float* vp = vladPart + ((size_t)(n*CHV_ + c2))*(K_*C_);
  #pragma unroll
  for (int mtl=0;mtl<2;++mtl){
    #pragma unroll
    for (int ct=0;ct<2;++ct){
      int c = wvc*32 + ct*16 + mrow;
      #pragma unroll
      for (int r=0;r<4;++r){
        int k = (mh*2+mtl)*16 + quad*4 + r;
        vp[k*C_ + c] = acc[mtl][ct][r];
      }
    }
  }
  if (t < K_){
    float s = s_part[0][t] + s_part[1][t] + s_part[2][t] + s_part[3][t];
    sumawPart[((size_t)n*CHV_ + c2)*K_ + t] = s;
  }
}

// ---------- K5: parallel chunk reduce + centroid term -> vlad ----------
__global__ __launch_bounds__(256) void k_vred(const float* __restrict__ vladPart,
                                              const float* __restrict__ sumawPart,
                                              const void* __restrict__ cen,
                                              const void* __restrict__ x,
                                              float* __restrict__ vlad){
  int f32 = is_f32((const unsigned short*)x);
  int tid = blockIdx.x*256 + threadIdx.x;       // < N_*K_*C_ = 262144
  int n = tid >> 13;
  int i = tid & 8191;
  int k = i >> 7;
  const float* vp = vladPart + (size_t)n*CHV_*(K_*C_) + i;
  float s = 0.f;
  #pragma unroll
  for (int ch=0;ch<CHV_;++ch) s += vp[(size_t)ch*(K_*C_)];
  float sw = 0.f;
  #pragma unroll
  for (int ch=0;ch<CHV_;++ch) sw += sumawPart[((size_t)n*CHV_ + ch)*K_ + k];
  float cv = f32 ? ((const float*)cen)[i] : b2f(((const bf16*)cen)[i]);
  vlad[tid] = s - cv*sw;
}

// ---------- K6: intra-norm * cluster_weights, global L2 norm, store ----------
__global__ __launch_bounds__(256) void k_final(const float* __restrict__ vlad,
                                               const void* __restrict__ clw,
                                               const void* __restrict__ x,
                                               void* __restrict__ out){
  __shared__ float s_v[K_*C_];
  __shared__ float s_ssk[K_];
  __shared__ float s_scale[K_];
  __shared__ float s_gs;
  int n = blockIdx.x, t = threadIdx.x;
  int f32 = is_f32((const unsigned short*)x);
  const float* vp = vlad + (size_t)n*K_*C_;
  for (int i=t;i<K_*C_;i+=256) s_v[i] = vp[i];
  __syncthreads();
  int k = t >> 2, q = t & 3;
  float ss = 0.f;
  for (int mm=0;mm<32;++mm){ float v = s_v[k*C_ + q + 4*mm]; ss += v*v; }
  ss += __shfl_down(ss, 2);
  ss += __shfl_down(ss, 1);
  if (q == 0) s_ssk[k] = ss;
  __syncthreads();
  if (t < K_){
    float cw = f32 ? ((const float*)clw)[t] : b2f(((const bf16*)clw)[t]);
    s_scale[t] = cw / fmaxf(sqrtf(s_ssk[t]), 1e-12f);
  }
  __syncthreads();
  if (t == 0){
    float gss = 0.f;
    for (int kk=0;kk<K_;++kk) gss += s_ssk[kk]*s_scale[kk]*s_scale[kk];
    s_gs = 1.f / fmaxf(sqrtf(gss), 1e-12f);
  }
  __syncthreads();
  float gsc = s_gs;
  if (f32){
    float* op = (float*)out + (size_t)n*K_*C_;
    for (int i=t;i<K_*C_;i+=256) op[i] = s_v[i]*s_scale[i>>7]*gsc;
  } else {
    bf16* op = (bf16*)out + (size_t)n*K_*C_;
    for (int i=t;i<K_*C_;i+=256) op[i] = __float2bfloat16(s_v[i]*s_scale[i>>7]*gsc);
  }
}

extern "C" void kernel_launch(void* const* d_in, const int* in_sizes, int n_in,
                              void* d_out, int out_size, void* d_ws, size_t ws_size,
                              hipStream_t stream){
  const void* x   = d_in[0];
  const void* cen = d_in[1];
  const void* cvw = d_in[2];
  const void* csw = d_in[3];
  const void* caw = d_in[4];
  const void* clw = d_in[5];

  char* ws = (char*)d_ws;
  bf16* WallF = (bf16*)ws;             ws += (size_t)M_*C_*2;        // 128 KB
  bf16* xnF   = (bf16*)ws;             ws += (size_t)N_*P_*C_*2;     // 18.87 MB
  bf16* xnG   = (bf16*)ws;             ws += (size_t)N_*C_*P_*2;     // 18.87 MB
  char* aBuf  = ws;                    ws += (size_t)N_*K_*P_*2;     // 9.44 MB
  unsigned short* a = (unsigned short*)aBuf;   // dead after k_vlad
  float* vlad = (float*)aBuf;                  // overlay: written by k_vred (1 MB)
  float* sal  = (float*)ws;            ws += (size_t)N_*K_*R_*4;     // 0.17 MB
  char* un = ws;
  float* salPart   = (float*)un;               // dead after k_salred
  float* sumawPart = (float*)un;               // overlay: written by k_vlad (147 KB)
  ws += (size_t)N_*NB_*K_*R_*4;                                      // 12.39 MB
  // vladPart overlays xnF (dead after k_gemm); N_*CHV_*K_*C_*4 == N_*P_*C_*2 exactly.
  float* vladPart = (float*)xnF;

  k_wall  <<<dim3(M_*C_/256),       256, 0, stream>>>(cvw, csw, caw, x, WallF);
  k_norm  <<<dim3(N_*P_/128),       256, 0, stream>>>(x, xnF, xnG);
  k_gemm  <<<dim3(NB_, N_),         512, 0, stream>>>(WallF, xnF, a, salPart);
  k_salred<<<dim3((N_*K_*R_+255)/256), 256, 0, stream>>>(salPart, sal);
  k_vlad  <<<dim3(CHV_, N_),        512, 0, stream>>>(xnG, a, sal, vladPart, sumawPart);
  k_vred  <<<dim3(N_*K_*C_/256),    256, 0, stream>>>(vladPart, sumawPart, cen, x, vlad);
  k_final <<<dim3(N_),              256, 0, stream>>>(vlad, clw, x, d_out);
}